// Round 10
// baseline (327.907 us; speedup 1.0000x reference)
//
#include <hip/hip_runtime.h>
#include <hip/hip_bf16.h>

#define NENT 40000
#define NREL 20
#define DIM 128
#define NBASIS 8
#define KTOT 1152              // 8*128 (G) + 128 (x)
#define P0END 20480            // pass split (320 tiles of 64)
#define SCANBLK 157            // ceil(40000/256)

typedef __attribute__((ext_vector_type(8))) short sh8;
typedef __attribute__((ext_vector_type(4))) float fx4;

__device__ __forceinline__ short f2bf(float f) {
    union { __hip_bfloat16 h; short s; } u;
    u.h = __float2bfloat16(f);
    return u.s;
}

// f32 -> bf16 copy (x panel for layer 1 + gather source)
__global__ void k_tobf(const float* __restrict__ x, ushort* __restrict__ xb, int nelem) {
    int i = (blockIdx.x * 256 + threadIdx.x) * 4;
    if (i >= nelem) return;
    float4 v = *(const float4*)(x + i);
    ushort4 o;
    o.x = (ushort)f2bf(v.x); o.y = (ushort)f2bf(v.y);
    o.z = (ushort)f2bf(v.z); o.w = (ushort)f2bf(v.w);
    *(ushort4*)(xb + i) = o;
}

// Fragment-order stacked B: ks 0..7 = basis[ks] (k-rows i), ks 8 = root.
// B-frag: lane holds B[k = kk*32 + lhi*8 + e][col = c*16 + l15].
__global__ void k_wfrag9(const float* __restrict__ basis, const float* __restrict__ root,
                         short* __restrict__ Wfb) {
    int t = blockIdx.x * 256 + threadIdx.x;
    if (t >= 9 * 16384) return;
    int ks = t / 16384;
    int rem = t & 16383;
    int i = rem >> 7, o = rem & 127;
    float v = (ks < 8) ? basis[ks * 16384 + i * 128 + o] : root[i * 128 + o];
    int c = o >> 4, l15 = o & 15;
    int kk = i >> 5, lhi = (i >> 3) & 3, e = i & 7;
    int lane = l15 + lhi * 16;
    Wfb[(size_t)ks * 16384 + (size_t)(((c * 4 + kk) * 64 + lane) << 3) + e] = f2bf(v);
}

__global__ void k_hist(const int* __restrict__ dst, int E, int* __restrict__ hist) {
    int e = blockIdx.x * 256 + threadIdx.x;
    if (e < E) atomicAdd(&hist[dst[e]], 1);
}

// -------- 3-phase parallel scan over NENT bins --------
__global__ void k_scan1(const int* __restrict__ hist, int* __restrict__ offs,
                        int* __restrict__ bsum) {
    __shared__ int ps[256];
    int t = threadIdx.x;
    int i = blockIdx.x * 256 + t;
    int v = (i < NENT) ? hist[i] : 0;
    ps[t] = v;
    __syncthreads();
    for (int off = 1; off < 256; off <<= 1) {
        int u = (t >= off) ? ps[t - off] : 0;
        __syncthreads();
        ps[t] += u;
        __syncthreads();
    }
    if (i < NENT) offs[i] = ps[t] - v;
    if (t == 255) bsum[blockIdx.x] = ps[255];
}

__global__ void k_scan2(int* __restrict__ bsum) {
    __shared__ int ps[256];
    int t = threadIdx.x;
    int v = (t < SCANBLK) ? bsum[t] : 0;
    ps[t] = v;
    __syncthreads();
    for (int off = 1; off < 256; off <<= 1) {
        int u = (t >= off) ? ps[t - off] : 0;
        __syncthreads();
        ps[t] += u;
        __syncthreads();
    }
    if (t < SCANBLK) bsum[t] = ps[t] - v;
}

__global__ void k_scan3(int* __restrict__ offs, int* __restrict__ cursor,
                        const int* __restrict__ bsum, int E) {
    int i = blockIdx.x * 256 + threadIdx.x;
    if (i < NENT) {
        int o = offs[i] + bsum[blockIdx.x];
        offs[i] = o;
        cursor[i] = o;
    }
    if (i == 0) offs[NENT] = E;
}

// counting-sort by dst: packed = src | et<<16
__global__ void k_scatter(const int* __restrict__ et, const int* __restrict__ srcA,
                          const int* __restrict__ dstA, int E,
                          int* __restrict__ cursor, unsigned* __restrict__ packed) {
    int e = blockIdx.x * 256 + threadIdx.x;
    if (e >= E) return;
    int pos = atomicAdd(&cursor[dstA[e]], 1);
    packed[pos] = (unsigned)srcA[e] | ((unsigned)et[e] << 16);
}

// One wave per dst node: G[n][b][:] = (1/deg) * sum_e comp[et,b]*x[src].
__global__ __launch_bounds__(256) void k_gather(
    const ushort* __restrict__ xb, const unsigned* __restrict__ packed,
    const int* __restrict__ offs, const float* __restrict__ comp,
    ushort* __restrict__ G, int n0, int n1) {
    __shared__ __align__(16) float cl[NREL * NBASIS];
    int t = threadIdx.x;
    if (t < NREL * NBASIS) cl[t] = comp[t];
    __syncthreads();
    int n = n0 + blockIdx.x * 4 + (t >> 6);
    if (n >= n1) return;
    int lane = t & 63;
    int beg = offs[n];
    int cnt = offs[n + 1] - beg;

    float a0[NBASIS], a1[NBASIS];
#pragma unroll
    for (int b = 0; b < NBASIS; ++b) { a0[b] = 0.f; a1[b] = 0.f; }

    const unsigned* xrow = (const unsigned*)xb + lane;
    unsigned pA = 0, pB = 0, rA = 0;
    if (cnt > 0) { pA = packed[beg]; rA = xrow[(size_t)(pA & 0xFFFFu) * 64]; }
    if (cnt > 1) pB = packed[beg + 1];

    for (int i = 0; i < cnt; ++i) {
        unsigned pC = (i + 2 < cnt) ? packed[beg + i + 2] : 0u;
        unsigned rB = xrow[(size_t)(pB & 0xFFFFu) * 64];
        float xlo = __uint_as_float(rA << 16);
        float xhi = __uint_as_float(rA & 0xFFFF0000u);
        int et = pA >> 16;
        float4 cwa = *(const float4*)&cl[et * NBASIS];
        float4 cwb = *(const float4*)&cl[et * NBASIS + 4];
        a0[0] += cwa.x * xlo; a1[0] += cwa.x * xhi;
        a0[1] += cwa.y * xlo; a1[1] += cwa.y * xhi;
        a0[2] += cwa.z * xlo; a1[2] += cwa.z * xhi;
        a0[3] += cwa.w * xlo; a1[3] += cwa.w * xhi;
        a0[4] += cwb.x * xlo; a1[4] += cwb.x * xhi;
        a0[5] += cwb.y * xlo; a1[5] += cwb.y * xhi;
        a0[6] += cwb.z * xlo; a1[6] += cwb.z * xhi;
        a0[7] += cwb.w * xlo; a1[7] += cwb.w * xhi;
        pA = pB; pB = pC; rA = rB;
    }

    float inv = 1.f / (float)(cnt < 1 ? 1 : cnt);
    unsigned* go = (unsigned*)(G + (size_t)(n - n0) * 1024) + lane;
#pragma unroll
    for (int b = 0; b < NBASIS; ++b) {
        unsigned lo = (unsigned)(ushort)f2bf(a0[b] * inv);
        unsigned hi = (unsigned)(ushort)f2bf(a1[b] * inv);
        go[b * 64] = lo | (hi << 16);
    }
}

// in-flight fragment buffer: one K-slice of A (2 row-groups) + B (4 col-frags)
struct Frag {
    sh8 a[2][4];
    sh8 b[4][4];
};

// raw async global load, 16B, immediate offset; compiler does NOT track this
// load's vmcnt — we wait manually (WAITV) before use.
#define GLD(dst, ptr, off)                                                 \
    asm volatile("global_load_dwordx4 %0, %1, off offset:%2"               \
                 : "=v"(dst) : "v"(ptr), "n"(off))

// counted wait + scheduler fence (rule #18: fence or MFMAs hoist past wait)
#define WAITV(N)                                                           \
    do {                                                                   \
        asm volatile("s_waitcnt vmcnt(" #N ")" ::: "memory");              \
        __builtin_amdgcn_sched_barrier(0);                                 \
    } while (0)

// issue one K-slice: 8 A-loads (from pa0/pa1 + AOFF) + 16 B-loads (bp0..bp3),
// then advance B pointers one slice (32768 B)
#define ISSUE(F, pa0, pa1, AOFF)                                           \
    do {                                                                   \
        GLD((F).a[0][0], pa0, (AOFF) + 0);                                 \
        GLD((F).a[0][1], pa0, (AOFF) + 64);                                \
        GLD((F).a[0][2], pa0, (AOFF) + 128);                               \
        GLD((F).a[0][3], pa0, (AOFF) + 192);                               \
        GLD((F).a[1][0], pa1, (AOFF) + 0);                                 \
        GLD((F).a[1][1], pa1, (AOFF) + 64);                                \
        GLD((F).a[1][2], pa1, (AOFF) + 128);                               \
        GLD((F).a[1][3], pa1, (AOFF) + 192);                               \
        GLD((F).b[0][0], bp0, 0);    GLD((F).b[0][1], bp0, 1024);          \
        GLD((F).b[0][2], bp0, 2048); GLD((F).b[0][3], bp0, 3072);          \
        GLD((F).b[1][0], bp1, 0);    GLD((F).b[1][1], bp1, 1024);          \
        GLD((F).b[1][2], bp1, 2048); GLD((F).b[1][3], bp1, 3072);          \
        GLD((F).b[2][0], bp2, 0);    GLD((F).b[2][1], bp2, 1024);          \
        GLD((F).b[2][2], bp2, 2048); GLD((F).b[2][3], bp2, 3072);          \
        GLD((F).b[3][0], bp3, 0);    GLD((F).b[3][1], bp3, 1024);          \
        GLD((F).b[3][2], bp3, 2048); GLD((F).b[3][3], bp3, 3072);          \
        bp0 += 16384; bp1 += 16384; bp2 += 16384; bp3 += 16384;            \
    } while (0)

// Dense MFMA GEMM with a hand-held depth-2 pipeline (3-buffer rotation):
// issue(k+2) overlaps step(k); vmcnt(24) keeps one slice in flight across
// each step. C[64 x 128] = [G | xpan] @ Wfb + bias. 2x2 wave grid.
__global__ __launch_bounds__(256, 1) void k_bgemm(
    const ushort* __restrict__ G, const ushort* __restrict__ xpan,
    const short* __restrict__ Wfb, const float* __restrict__ bias,
    ushort* __restrict__ outbf, float* __restrict__ outf, int n0, int act) {
    int t = threadIdx.x;
    int lane = t & 63, wid = t >> 6;
    int wr = wid >> 1, wc = wid & 1;          // 2x2 wave grid
    int l15 = lane & 15, lhi = lane >> 4;

    int row0 = n0 + blockIdx.x * 64 + wr * 32;       // wave's first row
    const ushort* Ar0 = G + (size_t)(row0 - n0 + l15) * 1024 + lhi * 8;
    const ushort* Ar1 = Ar0 + (size_t)16 * 1024;
    const ushort* Xr0 = xpan + (size_t)(row0 + l15) * 128 + lhi * 8;
    const ushort* Xr1 = Xr0 + (size_t)16 * 128;
    // B pointers, one per col-frag c (kk handled by the 1024B imm offsets)
    const ushort* bp0 = (const ushort*)Wfb + (size_t)(((wc * 4 + 0) * 4) * 64 + lane) * 8;
    const ushort* bp1 = (const ushort*)Wfb + (size_t)(((wc * 4 + 1) * 4) * 64 + lane) * 8;
    const ushort* bp2 = (const ushort*)Wfb + (size_t)(((wc * 4 + 2) * 4) * 64 + lane) * 8;
    const ushort* bp3 = (const ushort*)Wfb + (size_t)(((wc * 4 + 3) * 4) * 64 + lane) * 8;

    fx4 acc[2][4];
#pragma unroll
    for (int rg = 0; rg < 2; ++rg)
#pragma unroll
        for (int c = 0; c < 4; ++c) acc[rg][c] = (fx4){0.f, 0.f, 0.f, 0.f};

    auto step = [&](const Frag& F) {
#pragma unroll
        for (int rg = 0; rg < 2; ++rg)
#pragma unroll
            for (int c = 0; c < 4; ++c)
#pragma unroll
                for (int kk = 0; kk < 4; ++kk)
                    acc[rg][c] = __builtin_amdgcn_mfma_f32_16x16x32_bf16(
                        F.a[rg][kk], F.b[c][kk], acc[rg][c], 0, 0, 0);
    };

    Frag F0, F1, F2;
    ISSUE(F0, Ar0, Ar1, 0);                    // slice 0
    ISSUE(F1, Ar0, Ar1, 256);                  // slice 1
    WAITV(24); step(F0); ISSUE(F2, Ar0, Ar1, 512);    // s0 | issue s2
    WAITV(24); step(F1); ISSUE(F0, Ar0, Ar1, 768);    // s1 | issue s3
    WAITV(24); step(F2); ISSUE(F1, Ar0, Ar1, 1024);   // s2 | issue s4
    WAITV(24); step(F0); ISSUE(F2, Ar0, Ar1, 1280);   // s3 | issue s5
    WAITV(24); step(F1); ISSUE(F0, Ar0, Ar1, 1536);   // s4 | issue s6
    WAITV(24); step(F2); ISSUE(F1, Ar0, Ar1, 1792);   // s5 | issue s7
    WAITV(24); step(F0); ISSUE(F2, Xr0, Xr1, 0);      // s6 | issue s8 (root/x)
    WAITV(24); step(F1);                               // s7
    WAITV(0);  step(F2);                               // s8

    int orow0 = row0 + lhi * 4;   // + rg*16 + j
#pragma unroll
    for (int rg = 0; rg < 2; ++rg) {
#pragma unroll
        for (int c = 0; c < 4; ++c) {
            int col = wc * 64 + c * 16 + l15;
            float bv = bias[col];
#pragma unroll
            for (int j = 0; j < 4; ++j) {
                float v = acc[rg][c][j] + bv;
                if (act) {
                    v = tanhf(v);
                    outbf[(size_t)(orow0 + rg * 16 + j) * 128 + col] = (ushort)f2bf(v);
                } else {
                    outf[(size_t)(orow0 + rg * 16 + j) * 128 + col] = v;
                }
            }
        }
    }
}

__global__ void k_rel(const float* __restrict__ rel, const float* __restrict__ wrel,
                      float* __restrict__ out, int nrows) {
    int idx = blockIdx.x * 256 + threadIdx.x;
    if (idx >= nrows * DIM) return;
    int j = idx >> 7, o = idx & 127;
    float s = 0.f;
    for (int i = 0; i < DIM; ++i) s += rel[j * DIM + i] * wrel[i * DIM + o];
    out[idx] = s;
}

extern "C" void kernel_launch(void* const* d_in, const int* in_sizes, int n_in,
                              void* d_out, int out_size, void* d_ws, size_t ws_size,
                              hipStream_t stream) {
    const int* edge_index = (const int*)d_in[0];
    const int* edge_type  = (const int*)d_in[1];
    const float* init_embed = (const float*)d_in[2];
    const float* init_rel   = (const float*)d_in[3];
    const float* w_rel      = (const float*)d_in[4];
    const float* comp1  = (const float*)d_in[5];
    const float* basis1 = (const float*)d_in[6];
    const float* root1  = (const float*)d_in[7];
    const float* bias1  = (const float*)d_in[8];
    const float* comp2  = (const float*)d_in[9];
    const float* basis2 = (const float*)d_in[10];
    const float* root2  = (const float*)d_in[11];
    const float* bias2  = (const float*)d_in[12];

    int E = in_sizes[1];
    const int* src = edge_index;
    const int* dst = edge_index + E;
    int relrows = in_sizes[3] / DIM;   // 40

    // workspace layout (16B-aligned regions)
    short* Wfb1 = (short*)d_ws;                          // 9*16384 shorts
    short* Wfb2 = Wfb1 + (size_t)9 * 16384;
    ushort* xb  = (ushort*)(Wfb2 + (size_t)9 * 16384);   // 40000*128 bf16
    ushort* hb  = xb + (size_t)NENT * DIM;               // 40000*128 bf16
    ushort* G   = hb + (size_t)NENT * DIM;               // 20480*1024 bf16 (42 MB)
    int* hist   = (int*)(G + (size_t)P0END * 1024);      // 40000 (pad 40004)
    int* offs   = hist + 40004;
    int* cursor = offs + 40004;
    int* bsum   = cursor + 40004;                        // 157 (pad 160)
    unsigned* packed = (unsigned*)(bsum + 160);          // E

    float* outx = (float*)d_out;
    float* outr = outx + (size_t)NENT * DIM;

    hipMemsetAsync(hist, 0, NENT * sizeof(int), stream);

    k_tobf<<<(NENT * DIM / 4 + 255) / 256, 256, 0, stream>>>(init_embed, xb, NENT * DIM);
    k_wfrag9<<<(9 * 16384 + 255) / 256, 256, 0, stream>>>(basis1, root1, Wfb1);
    k_wfrag9<<<(9 * 16384 + 255) / 256, 256, 0, stream>>>(basis2, root2, Wfb2);
    k_hist<<<(E + 255) / 256, 256, 0, stream>>>(dst, E, hist);
    k_scan1<<<SCANBLK, 256, 0, stream>>>(hist, offs, bsum);
    k_scan2<<<1, 256, 0, stream>>>(bsum);
    k_scan3<<<SCANBLK, 256, 0, stream>>>(offs, cursor, bsum, E);
    k_scatter<<<(E + 255) / 256, 256, 0, stream>>>(edge_type, src, dst, E, cursor, packed);

    // layer 1: hb = bf16(tanh(G@W~1 + x@root1 + bias1)), two node passes
    k_gather<<<P0END / 4, 256, 0, stream>>>(xb, packed, offs, comp1, G, 0, P0END);
    k_bgemm<<<P0END / 64, 256, 0, stream>>>(G, xb, Wfb1, bias1, hb, outx, 0, 1);
    k_gather<<<(NENT - P0END) / 4, 256, 0, stream>>>(xb, packed, offs, comp1, G, P0END, NENT);
    k_bgemm<<<(NENT - P0END) / 64, 256, 0, stream>>>(G, xb, Wfb1, bias1, hb, outx, P0END, 1);

    // layer 2: out = G@W~2 + h@root2 + bias2 (f32 to d_out)
    k_gather<<<P0END / 4, 256, 0, stream>>>(hb, packed, offs, comp2, G, 0, P0END);
    k_bgemm<<<P0END / 64, 256, 0, stream>>>(G, hb, Wfb2, bias2, hb, outx, 0, 0);
    k_gather<<<(NENT - P0END) / 4, 256, 0, stream>>>(hb, packed, offs, comp2, G, P0END, NENT);
    k_bgemm<<<(NENT - P0END) / 64, 256, 0, stream>>>(G, hb, Wfb2, bias2, hb, outx, P0END, 0);

    // relation output: r = init_rel @ w_rel
    k_rel<<<(relrows * DIM + 255) / 256, 256, 0, stream>>>(init_rel, w_rel, outr, relrows);
}

// Round 11
// 298.317 us; speedup vs baseline: 1.0992x; 1.0992x over previous
//
#include <hip/hip_runtime.h>
#include <hip/hip_bf16.h>

#define NENT 40000
#define NREL 20
#define DIM 128
#define NBASIS 8
#define TILE 32                // nodes per fused block
#define SCANBLK 157            // ceil(40000/256)

typedef __attribute__((ext_vector_type(8))) short sh8;
typedef __attribute__((ext_vector_type(4))) float fx4;

__device__ __forceinline__ short f2bf(float f) {
    union { __hip_bfloat16 h; short s; } u;
    u.h = __float2bfloat16(f);
    return u.s;
}

// f32 -> bf16 copy (x panel for layer 1 + gather source)
__global__ void k_tobf(const float* __restrict__ x, ushort* __restrict__ xb, int nelem) {
    int i = (blockIdx.x * 256 + threadIdx.x) * 4;
    if (i >= nelem) return;
    float4 v = *(const float4*)(x + i);
    ushort4 o;
    o.x = (ushort)f2bf(v.x); o.y = (ushort)f2bf(v.y);
    o.z = (ushort)f2bf(v.z); o.w = (ushort)f2bf(v.w);
    *(ushort4*)(xb + i) = o;
}

// Fragment-order stacked B: ks 0..7 = basis[ks] (k-rows i), ks 8 = root.
// B-frag: lane holds B[k = kk*32 + lhi*8 + e][col = c*16 + l15].
__global__ void k_wfrag9(const float* __restrict__ basis, const float* __restrict__ root,
                         short* __restrict__ Wfb) {
    int t = blockIdx.x * 256 + threadIdx.x;
    if (t >= 9 * 16384) return;
    int ks = t / 16384;
    int rem = t & 16383;
    int i = rem >> 7, o = rem & 127;
    float v = (ks < 8) ? basis[ks * 16384 + i * 128 + o] : root[i * 128 + o];
    int c = o >> 4, l15 = o & 15;
    int kk = i >> 5, lhi = (i >> 3) & 3, e = i & 7;
    int lane = l15 + lhi * 16;
    Wfb[(size_t)ks * 16384 + (size_t)(((c * 4 + kk) * 64 + lane) << 3) + e] = f2bf(v);
}

__global__ void k_hist(const int* __restrict__ dst, int E, int* __restrict__ hist) {
    int e = blockIdx.x * 256 + threadIdx.x;
    if (e < E) atomicAdd(&hist[dst[e]], 1);
}

// -------- 3-phase parallel scan over NENT bins --------
__global__ void k_scan1(const int* __restrict__ hist, int* __restrict__ offs,
                        int* __restrict__ bsum) {
    __shared__ int ps[256];
    int t = threadIdx.x;
    int i = blockIdx.x * 256 + t;
    int v = (i < NENT) ? hist[i] : 0;
    ps[t] = v;
    __syncthreads();
    for (int off = 1; off < 256; off <<= 1) {
        int u = (t >= off) ? ps[t - off] : 0;
        __syncthreads();
        ps[t] += u;
        __syncthreads();
    }
    if (i < NENT) offs[i] = ps[t] - v;
    if (t == 255) bsum[blockIdx.x] = ps[255];
}

__global__ void k_scan2(int* __restrict__ bsum) {
    __shared__ int ps[256];
    int t = threadIdx.x;
    int v = (t < SCANBLK) ? bsum[t] : 0;
    ps[t] = v;
    __syncthreads();
    for (int off = 1; off < 256; off <<= 1) {
        int u = (t >= off) ? ps[t - off] : 0;
        __syncthreads();
        ps[t] += u;
        __syncthreads();
    }
    if (t < SCANBLK) bsum[t] = ps[t] - v;
}

__global__ void k_scan3(int* __restrict__ offs, int* __restrict__ cursor,
                        const int* __restrict__ bsum, int E) {
    int i = blockIdx.x * 256 + threadIdx.x;
    if (i < NENT) {
        int o = offs[i] + bsum[blockIdx.x];
        offs[i] = o;
        cursor[i] = o;
    }
    if (i == 0) offs[NENT] = E;
}

// counting-sort by dst: packed = src | et<<16
__global__ void k_scatter(const int* __restrict__ et, const int* __restrict__ srcA,
                          const int* __restrict__ dstA, int E,
                          int* __restrict__ cursor, unsigned* __restrict__ packed) {
    int e = blockIdx.x * 256 + threadIdx.x;
    if (e >= E) return;
    int pos = atomicAdd(&cursor[dstA[e]], 1);
    packed[pos] = (unsigned)srcA[e] | ((unsigned)et[e] << 16);
}

// Fused RGCN layer: block = 32 dst nodes, 8 waves.
// Phase 1: wave w gathers nodes w*4..w*4+3 entirely in registers
//   (G-row[b][:] = (1/deg) * sum_e comp[et,b]*x[src]; lane owns cols 2l,2l+1),
//   then writes bf16 G-rows into a 64KB XOR-swizzled LDS tile. No atomics.
// Phase 2: C[32x128] = [G_lds(1024) | x(128)] @ Wfb + bias via MFMA;
//   A-frags ds_read_b128 (swizzle kills stride-2048 conflicts), B from L2.
__global__ __launch_bounds__(512) void k_fused(
    const ushort* __restrict__ xb, const unsigned* __restrict__ packed,
    const int* __restrict__ offs, const float* __restrict__ comp,
    const short* __restrict__ Wfb, const float* __restrict__ bias,
    ushort* __restrict__ outbf, float* __restrict__ outf, int act) {
    __shared__ __align__(16) ushort Gl[TILE * 1024];   // 64KB
    __shared__ __align__(16) float cl[NREL * NBASIS];

    int t = threadIdx.x;
    int lane = t & 63, wid = t >> 6;
    if (t < NREL * NBASIS) cl[t] = comp[t];
    __syncthreads();

    int tile0 = blockIdx.x * TILE;

    // ---- phase 1: gather (4 nodes per wave, register accumulation) ----
    const unsigned* xrow = (const unsigned*)xb + lane;
    for (int sub = 0; sub < 4; ++sub) {
        int row = wid * 4 + sub;             // 0..31
        int n = tile0 + row;
        int beg = offs[n];
        int cnt = offs[n + 1] - beg;

        float a0[NBASIS], a1[NBASIS];
#pragma unroll
        for (int b = 0; b < NBASIS; ++b) { a0[b] = 0.f; a1[b] = 0.f; }

        unsigned pA = 0, pB = 0, rA = 0;
        if (cnt > 0) { pA = packed[beg]; rA = xrow[(size_t)(pA & 0xFFFFu) * 64]; }
        if (cnt > 1) pB = packed[beg + 1];

        for (int i = 0; i < cnt; ++i) {
            unsigned pC = (i + 2 < cnt) ? packed[beg + i + 2] : 0u;
            unsigned rB = xrow[(size_t)(pB & 0xFFFFu) * 64];
            float xlo = __uint_as_float(rA << 16);
            float xhi = __uint_as_float(rA & 0xFFFF0000u);
            int et = pA >> 16;
            float4 cwa = *(const float4*)&cl[et * NBASIS];
            float4 cwb = *(const float4*)&cl[et * NBASIS + 4];
            a0[0] += cwa.x * xlo; a1[0] += cwa.x * xhi;
            a0[1] += cwa.y * xlo; a1[1] += cwa.y * xhi;
            a0[2] += cwa.z * xlo; a1[2] += cwa.z * xhi;
            a0[3] += cwa.w * xlo; a1[3] += cwa.w * xhi;
            a0[4] += cwb.x * xlo; a1[4] += cwb.x * xhi;
            a0[5] += cwb.y * xlo; a1[5] += cwb.y * xhi;
            a0[6] += cwb.z * xlo; a1[6] += cwb.z * xhi;
            a0[7] += cwb.w * xlo; a1[7] += cwb.w * xhi;
            pA = pB; pB = pC; rA = rB;
        }

        float inv = 1.f / (float)(cnt < 1 ? 1 : cnt);
#pragma unroll
        for (int b = 0; b < NBASIS; ++b) {
            unsigned lo = (unsigned)(ushort)f2bf(a0[b] * inv);
            unsigned hi = (unsigned)(ushort)f2bf(a1[b] * inv);
            unsigned byteoff = (unsigned)(row * 2048 + b * 256 + lane * 4);
            byteoff ^= (unsigned)((row & 7) << 4);   // bank swizzle
            *(unsigned*)((char*)Gl + byteoff) = lo | (hi << 16);
        }
    }
    __syncthreads();

    // ---- phase 2: MFMA GEMM ----
    int wr = wid >> 2, wc = wid & 3;          // 2 row-groups x 4 col-groups
    int l15 = lane & 15, lhi = lane >> 4;
    int arow = wr * 16 + l15;                 // LDS row this lane reads

    fx4 acc0 = (fx4){0.f, 0.f, 0.f, 0.f};
    fx4 acc1 = (fx4){0.f, 0.f, 0.f, 0.f};

    const ushort* Xr = xb + (size_t)(tile0 + wr * 16 + l15) * 128 + lhi * 8;
    const sh8* W8 = (const sh8*)Wfb;
    int c0 = wc * 2, c1 = wc * 2 + 1;

#pragma unroll
    for (int ks = 0; ks < 9; ++ks) {
        sh8 a[4];
        if (ks < 8) {
#pragma unroll
            for (int kk = 0; kk < 4; ++kk) {
                unsigned byteoff = (unsigned)(arow * 2048 + ks * 256 + kk * 64 + lhi * 16);
                byteoff ^= (unsigned)((arow & 7) << 4);
                a[kk] = *(const sh8*)((const char*)Gl + byteoff);
            }
        } else {
#pragma unroll
            for (int kk = 0; kk < 4; ++kk) a[kk] = *(const sh8*)(Xr + kk * 32);
        }
#pragma unroll
        for (int kk = 0; kk < 4; ++kk) {
            sh8 b0 = W8[(size_t)ks * 2048 + (size_t)((c0 * 4 + kk) * 64 + lane)];
            sh8 b1 = W8[(size_t)ks * 2048 + (size_t)((c1 * 4 + kk) * 64 + lane)];
            acc0 = __builtin_amdgcn_mfma_f32_16x16x32_bf16(a[kk], b0, acc0, 0, 0, 0);
            acc1 = __builtin_amdgcn_mfma_f32_16x16x32_bf16(a[kk], b1, acc1, 0, 0, 0);
        }
    }

    // bias + act + store
    int orow0 = tile0 + wr * 16 + lhi * 4;
#pragma unroll
    for (int cc = 0; cc < 2; ++cc) {
        int col = wc * 32 + cc * 16 + l15;
        float bv = bias[col];
        const fx4& ac = cc ? acc1 : acc0;
#pragma unroll
        for (int j = 0; j < 4; ++j) {
            float v = ac[j] + bv;
            if (act) {
                v = tanhf(v);
                outbf[(size_t)(orow0 + j) * 128 + col] = (ushort)f2bf(v);
            } else {
                outf[(size_t)(orow0 + j) * 128 + col] = v;
            }
        }
    }
}

__global__ void k_rel(const float* __restrict__ rel, const float* __restrict__ wrel,
                      float* __restrict__ out, int nrows) {
    int idx = blockIdx.x * 256 + threadIdx.x;
    if (idx >= nrows * DIM) return;
    int j = idx >> 7, o = idx & 127;
    float s = 0.f;
    for (int i = 0; i < DIM; ++i) s += rel[j * DIM + i] * wrel[i * DIM + o];
    out[idx] = s;
}

extern "C" void kernel_launch(void* const* d_in, const int* in_sizes, int n_in,
                              void* d_out, int out_size, void* d_ws, size_t ws_size,
                              hipStream_t stream) {
    const int* edge_index = (const int*)d_in[0];
    const int* edge_type  = (const int*)d_in[1];
    const float* init_embed = (const float*)d_in[2];
    const float* init_rel   = (const float*)d_in[3];
    const float* w_rel      = (const float*)d_in[4];
    const float* comp1  = (const float*)d_in[5];
    const float* basis1 = (const float*)d_in[6];
    const float* root1  = (const float*)d_in[7];
    const float* bias1  = (const float*)d_in[8];
    const float* comp2  = (const float*)d_in[9];
    const float* basis2 = (const float*)d_in[10];
    const float* root2  = (const float*)d_in[11];
    const float* bias2  = (const float*)d_in[12];

    int E = in_sizes[1];
    const int* src = edge_index;
    const int* dst = edge_index + E;
    int relrows = in_sizes[3] / DIM;   // 40

    // workspace layout (16B-aligned regions)
    short* Wfb1 = (short*)d_ws;                          // 9*16384 shorts
    short* Wfb2 = Wfb1 + (size_t)9 * 16384;
    ushort* xb  = (ushort*)(Wfb2 + (size_t)9 * 16384);   // 40000*128 bf16
    ushort* hb  = xb + (size_t)NENT * DIM;               // 40000*128 bf16
    int* hist   = (int*)(hb + (size_t)NENT * DIM);       // 40000 (pad 40004)
    int* offs   = hist + 40004;
    int* cursor = offs + 40004;
    int* bsum   = cursor + 40004;                        // 157 (pad 160)
    unsigned* packed = (unsigned*)(bsum + 160);          // E

    float* outx = (float*)d_out;
    float* outr = outx + (size_t)NENT * DIM;

    hipMemsetAsync(hist, 0, NENT * sizeof(int), stream);

    k_tobf<<<(NENT * DIM / 4 + 255) / 256, 256, 0, stream>>>(init_embed, xb, NENT * DIM);
    k_wfrag9<<<(9 * 16384 + 255) / 256, 256, 0, stream>>>(basis1, root1, Wfb1);
    k_wfrag9<<<(9 * 16384 + 255) / 256, 256, 0, stream>>>(basis2, root2, Wfb2);
    k_hist<<<(E + 255) / 256, 256, 0, stream>>>(dst, E, hist);
    k_scan1<<<SCANBLK, 256, 0, stream>>>(hist, offs, bsum);
    k_scan2<<<1, 256, 0, stream>>>(bsum);
    k_scan3<<<SCANBLK, 256, 0, stream>>>(offs, cursor, bsum, E);
    k_scatter<<<(E + 255) / 256, 256, 0, stream>>>(edge_type, src, dst, E, cursor, packed);

    // layer 1: hb = bf16(tanh(gather@W~1 + x@root1 + bias1))
    k_fused<<<NENT / TILE, 512, 0, stream>>>(xb, packed, offs, comp1, Wfb1, bias1,
                                             hb, outx, 1);
    // layer 2: out = gather@W~2 + h@root2 + bias2 (f32 to d_out)
    k_fused<<<NENT / TILE, 512, 0, stream>>>(hb, packed, offs, comp2, Wfb2, bias2,
                                             hb, outx, 0);

    // relation output: r = init_rel @ w_rel
    k_rel<<<(relrows * DIM + 255) / 256, 256, 0, stream>>>(init_rel, w_rel, outr, relrows);
}

// Round 12
// 262.120 us; speedup vs baseline: 1.2510x; 1.1381x over previous
//
#include <hip/hip_runtime.h>
#include <hip/hip_bf16.h>

#define NENT 40000
#define NREL 20
#define DIM 128
#define NBASIS 8
#define TILE 32                // nodes per fused block
#define PKCAP 1024             // LDS-staged packed entries per tile (avg ~512)
#define SCANBLK 157            // ceil(40000/256)

typedef __attribute__((ext_vector_type(8))) short sh8;
typedef __attribute__((ext_vector_type(4))) float fx4;

__device__ __forceinline__ short f2bf(float f) {
    union { __hip_bfloat16 h; short s; } u;
    u.h = __float2bfloat16(f);
    return u.s;
}

// f32 -> bf16 copy (x panel for layer 1 + gather source)
__global__ void k_tobf(const float* __restrict__ x, ushort* __restrict__ xb, int nelem) {
    int i = (blockIdx.x * 256 + threadIdx.x) * 4;
    if (i >= nelem) return;
    float4 v = *(const float4*)(x + i);
    ushort4 o;
    o.x = (ushort)f2bf(v.x); o.y = (ushort)f2bf(v.y);
    o.z = (ushort)f2bf(v.z); o.w = (ushort)f2bf(v.w);
    *(ushort4*)(xb + i) = o;
}

// Fragment-order stacked B: ks 0..7 = basis[ks] (k-rows i), ks 8 = root.
// B-frag: lane holds B[k = kk*32 + lhi*8 + e][col = c*16 + l15].
__global__ void k_wfrag9(const float* __restrict__ basis, const float* __restrict__ root,
                         short* __restrict__ Wfb) {
    int t = blockIdx.x * 256 + threadIdx.x;
    if (t >= 9 * 16384) return;
    int ks = t / 16384;
    int rem = t & 16383;
    int i = rem >> 7, o = rem & 127;
    float v = (ks < 8) ? basis[ks * 16384 + i * 128 + o] : root[i * 128 + o];
    int c = o >> 4, l15 = o & 15;
    int kk = i >> 5, lhi = (i >> 3) & 3, e = i & 7;
    int lane = l15 + lhi * 16;
    Wfb[(size_t)ks * 16384 + (size_t)(((c * 4 + kk) * 64 + lane) << 3) + e] = f2bf(v);
}

__global__ void k_hist(const int* __restrict__ dst, int E, int* __restrict__ hist) {
    int e = blockIdx.x * 256 + threadIdx.x;
    if (e < E) atomicAdd(&hist[dst[e]], 1);
}

// -------- 3-phase parallel scan over NENT bins --------
__global__ void k_scan1(const int* __restrict__ hist, int* __restrict__ offs,
                        int* __restrict__ bsum) {
    __shared__ int ps[256];
    int t = threadIdx.x;
    int i = blockIdx.x * 256 + t;
    int v = (i < NENT) ? hist[i] : 0;
    ps[t] = v;
    __syncthreads();
    for (int off = 1; off < 256; off <<= 1) {
        int u = (t >= off) ? ps[t - off] : 0;
        __syncthreads();
        ps[t] += u;
        __syncthreads();
    }
    if (i < NENT) offs[i] = ps[t] - v;
    if (t == 255) bsum[blockIdx.x] = ps[255];
}

__global__ void k_scan2(int* __restrict__ bsum) {
    __shared__ int ps[256];
    int t = threadIdx.x;
    int v = (t < SCANBLK) ? bsum[t] : 0;
    ps[t] = v;
    __syncthreads();
    for (int off = 1; off < 256; off <<= 1) {
        int u = (t >= off) ? ps[t - off] : 0;
        __syncthreads();
        ps[t] += u;
        __syncthreads();
    }
    if (t < SCANBLK) bsum[t] = ps[t] - v;
}

__global__ void k_scan3(int* __restrict__ offs, int* __restrict__ cursor,
                        const int* __restrict__ bsum, int E) {
    int i = blockIdx.x * 256 + threadIdx.x;
    if (i < NENT) {
        int o = offs[i] + bsum[blockIdx.x];
        offs[i] = o;
        cursor[i] = o;
    }
    if (i == 0) offs[NENT] = E;
}

// counting-sort by dst: packed = src | et<<16
__global__ void k_scatter(const int* __restrict__ et, const int* __restrict__ srcA,
                          const int* __restrict__ dstA, int E,
                          int* __restrict__ cursor, unsigned* __restrict__ packed) {
    int e = blockIdx.x * 256 + threadIdx.x;
    if (e >= E) return;
    int pos = atomicAdd(&cursor[dstA[e]], 1);
    packed[pos] = (unsigned)srcA[e] | ((unsigned)et[e] << 16);
}

// Fused RGCN layer: block = 32 dst nodes, 8 waves.
// Phase 1: packed staged in LDS; wave w gathers nodes w*4..w*4+3 in registers
//   with 8-edge batches, A/B ping-pong (8 x-row loads in flight); writes bf16
//   G-rows to XOR-swizzled LDS. No atomics.
// Phase 2: C[32x128] = [G_lds(1024) | x(128)] @ Wfb + bias via MFMA.
__global__ __launch_bounds__(512) void k_fused(
    const ushort* __restrict__ xb, const unsigned* __restrict__ packed,
    const int* __restrict__ offs, const float* __restrict__ comp,
    const short* __restrict__ Wfb, const float* __restrict__ bias,
    ushort* __restrict__ outbf, float* __restrict__ outf, int act) {
    __shared__ __align__(16) ushort Gl[TILE * 1024];   // 64KB
    __shared__ __align__(16) float cl[NREL * NBASIS];
    __shared__ __align__(16) unsigned pkl[PKCAP];      // 4KB

    int t = threadIdx.x;
    int lane = t & 63, wid = t >> 6;
    if (t < NREL * NBASIS) cl[t] = comp[t];

    int tile0 = blockIdx.x * TILE;
    int base = offs[tile0];
    int totE = offs[tile0 + TILE] - base;
    for (int i = t; i < totE && i < PKCAP; i += 512) pkl[i] = packed[base + i];
    __syncthreads();

    // ---- phase 1: gather (4 nodes per wave, 8-edge batched pipeline) ----
    const unsigned* xrow = (const unsigned*)xb + lane;
    for (int sub = 0; sub < 4; ++sub) {
        int row = wid * 4 + sub;             // 0..31
        int n = tile0 + row;
        int begg = offs[n];
        int cnt = offs[n + 1] - begg;
        int begl = begg - base;

        float a0[NBASIS], a1[NBASIS];
#pragma unroll
        for (int b = 0; b < NBASIS; ++b) { a0[b] = 0.f; a1[b] = 0.f; }

        if (cnt > 0) {
            unsigned p0v = (begl < PKCAP) ? pkl[begl] : packed[begg];

            auto ldp = [&](int i0, unsigned (&p)[8]) {
#pragma unroll
                for (int u = 0; u < 8; ++u) {
                    int i = i0 + u;
                    int li = begl + i;
                    unsigned v = p0v;
                    if (i < cnt) v = (li < PKCAP) ? pkl[li] : packed[base + li];
                    p[u] = v;
                }
            };
            auto ldr = [&](const unsigned (&p)[8], unsigned (&r)[8]) {
#pragma unroll
                for (int u = 0; u < 8; ++u)
                    r[u] = xrow[(size_t)(p[u] & 0xFFFFu) * 64];
            };
            auto proc = [&](int i0, const unsigned (&p)[8], const unsigned (&r)[8]) {
#pragma unroll
                for (int u = 0; u < 8; ++u) {
                    if (i0 + u < cnt) {      // wave-uniform branch
                        float xlo = __uint_as_float(r[u] << 16);
                        float xhi = __uint_as_float(r[u] & 0xFFFF0000u);
                        int et = p[u] >> 16;
                        float4 cwa = *(const float4*)&cl[et * NBASIS];
                        float4 cwb = *(const float4*)&cl[et * NBASIS + 4];
                        a0[0] += cwa.x * xlo; a1[0] += cwa.x * xhi;
                        a0[1] += cwa.y * xlo; a1[1] += cwa.y * xhi;
                        a0[2] += cwa.z * xlo; a1[2] += cwa.z * xhi;
                        a0[3] += cwa.w * xlo; a1[3] += cwa.w * xhi;
                        a0[4] += cwb.x * xlo; a1[4] += cwb.x * xhi;
                        a0[5] += cwb.y * xlo; a1[5] += cwb.y * xhi;
                        a0[6] += cwb.z * xlo; a1[6] += cwb.z * xhi;
                        a0[7] += cwb.w * xlo; a1[7] += cwb.w * xhi;
                    }
                }
            };

            unsigned pA[8], rA[8], pB[8], rB[8];
            ldp(0, pA); ldr(pA, rA);
            int i0 = 0;
            while (true) {
                if (i0 + 8 < cnt) { ldp(i0 + 8, pB); ldr(pB, rB); }
                proc(i0, pA, rA);
                i0 += 8;
                if (i0 >= cnt) break;
                if (i0 + 8 < cnt) { ldp(i0 + 8, pA); ldr(pA, rA); }
                proc(i0, pB, rB);
                i0 += 8;
                if (i0 >= cnt) break;
            }
        }

        float inv = 1.f / (float)(cnt < 1 ? 1 : cnt);
#pragma unroll
        for (int b = 0; b < NBASIS; ++b) {
            unsigned lo = (unsigned)(ushort)f2bf(a0[b] * inv);
            unsigned hi = (unsigned)(ushort)f2bf(a1[b] * inv);
            unsigned byteoff = (unsigned)(row * 2048 + b * 256 + lane * 4);
            byteoff ^= (unsigned)((row & 7) << 4);   // bank swizzle
            *(unsigned*)((char*)Gl + byteoff) = lo | (hi << 16);
        }
    }
    __syncthreads();

    // ---- phase 2: MFMA GEMM ----
    int wr = wid >> 2, wc = wid & 3;          // 2 row-groups x 4 col-groups
    int l15 = lane & 15, lhi = lane >> 4;
    int arow = wr * 16 + l15;                 // LDS row this lane reads

    fx4 acc0 = (fx4){0.f, 0.f, 0.f, 0.f};
    fx4 acc1 = (fx4){0.f, 0.f, 0.f, 0.f};

    const ushort* Xr = xb + (size_t)(tile0 + wr * 16 + l15) * 128 + lhi * 8;
    const sh8* W8 = (const sh8*)Wfb;
    int c0 = wc * 2, c1 = wc * 2 + 1;

#pragma unroll
    for (int ks = 0; ks < 9; ++ks) {
        sh8 a[4];
        if (ks < 8) {
#pragma unroll
            for (int kk = 0; kk < 4; ++kk) {
                unsigned byteoff = (unsigned)(arow * 2048 + ks * 256 + kk * 64 + lhi * 16);
                byteoff ^= (unsigned)((arow & 7) << 4);
                a[kk] = *(const sh8*)((const char*)Gl + byteoff);
            }
        } else {
#pragma unroll
            for (int kk = 0; kk < 4; ++kk) a[kk] = *(const sh8*)(Xr + kk * 32);
        }
#pragma unroll
        for (int kk = 0; kk < 4; ++kk) {
            sh8 b0 = W8[(size_t)ks * 2048 + (size_t)((c0 * 4 + kk) * 64 + lane)];
            sh8 b1 = W8[(size_t)ks * 2048 + (size_t)((c1 * 4 + kk) * 64 + lane)];
            acc0 = __builtin_amdgcn_mfma_f32_16x16x32_bf16(a[kk], b0, acc0, 0, 0, 0);
            acc1 = __builtin_amdgcn_mfma_f32_16x16x32_bf16(a[kk], b1, acc1, 0, 0, 0);
        }
    }

    // bias + act + store
    int orow0 = tile0 + wr * 16 + lhi * 4;
#pragma unroll
    for (int cc = 0; cc < 2; ++cc) {
        int col = wc * 32 + cc * 16 + l15;
        float bv = bias[col];
        const fx4& ac = cc ? acc1 : acc0;
#pragma unroll
        for (int j = 0; j < 4; ++j) {
            float v = ac[j] + bv;
            if (act) {
                v = tanhf(v);
                outbf[(size_t)(orow0 + j) * 128 + col] = (ushort)f2bf(v);
            } else {
                outf[(size_t)(orow0 + j) * 128 + col] = v;
            }
        }
    }
}

__global__ void k_rel(const float* __restrict__ rel, const float* __restrict__ wrel,
                      float* __restrict__ out, int nrows) {
    int idx = blockIdx.x * 256 + threadIdx.x;
    if (idx >= nrows * DIM) return;
    int j = idx >> 7, o = idx & 127;
    float s = 0.f;
    for (int i = 0; i < DIM; ++i) s += rel[j * DIM + i] * wrel[i * DIM + o];
    out[idx] = s;
}

extern "C" void kernel_launch(void* const* d_in, const int* in_sizes, int n_in,
                              void* d_out, int out_size, void* d_ws, size_t ws_size,
                              hipStream_t stream) {
    const int* edge_index = (const int*)d_in[0];
    const int* edge_type  = (const int*)d_in[1];
    const float* init_embed = (const float*)d_in[2];
    const float* init_rel   = (const float*)d_in[3];
    const float* w_rel      = (const float*)d_in[4];
    const float* comp1  = (const float*)d_in[5];
    const float* basis1 = (const float*)d_in[6];
    const float* root1  = (const float*)d_in[7];
    const float* bias1  = (const float*)d_in[8];
    const float* comp2  = (const float*)d_in[9];
    const float* basis2 = (const float*)d_in[10];
    const float* root2  = (const float*)d_in[11];
    const float* bias2  = (const float*)d_in[12];

    int E = in_sizes[1];
    const int* src = edge_index;
    const int* dst = edge_index + E;
    int relrows = in_sizes[3] / DIM;   // 40

    // workspace layout (16B-aligned regions)
    short* Wfb1 = (short*)d_ws;                          // 9*16384 shorts
    short* Wfb2 = Wfb1 + (size_t)9 * 16384;
    ushort* xb  = (ushort*)(Wfb2 + (size_t)9 * 16384);   // 40000*128 bf16
    ushort* hb  = xb + (size_t)NENT * DIM;               // 40000*128 bf16
    int* hist   = (int*)(hb + (size_t)NENT * DIM);       // 40000 (pad 40004)
    int* offs   = hist + 40004;
    int* cursor = offs + 40004;
    int* bsum   = cursor + 40004;                        // 157 (pad 160)
    unsigned* packed = (unsigned*)(bsum + 160);          // E

    float* outx = (float*)d_out;
    float* outr = outx + (size_t)NENT * DIM;

    hipMemsetAsync(hist, 0, NENT * sizeof(int), stream);

    k_tobf<<<(NENT * DIM / 4 + 255) / 256, 256, 0, stream>>>(init_embed, xb, NENT * DIM);
    k_wfrag9<<<(9 * 16384 + 255) / 256, 256, 0, stream>>>(basis1, root1, Wfb1);
    k_wfrag9<<<(9 * 16384 + 255) / 256, 256, 0, stream>>>(basis2, root2, Wfb2);
    k_hist<<<(E + 255) / 256, 256, 0, stream>>>(dst, E, hist);
    k_scan1<<<SCANBLK, 256, 0, stream>>>(hist, offs, bsum);
    k_scan2<<<1, 256, 0, stream>>>(bsum);
    k_scan3<<<SCANBLK, 256, 0, stream>>>(offs, cursor, bsum, E);
    k_scatter<<<(E + 255) / 256, 256, 0, stream>>>(edge_type, src, dst, E, cursor, packed);

    // layer 1: hb = bf16(tanh(gather@W~1 + x@root1 + bias1))
    k_fused<<<NENT / TILE, 512, 0, stream>>>(xb, packed, offs, comp1, Wfb1, bias1,
                                             hb, outx, 1);
    // layer 2: out = gather@W~2 + h@root2 + bias2 (f32 to d_out)
    k_fused<<<NENT / TILE, 512, 0, stream>>>(hb, packed, offs, comp2, Wfb2, bias2,
                                             hb, outx, 0);

    // relation output: r = init_rel @ w_rel
    k_rel<<<(relrows * DIM + 255) / 256, 256, 0, stream>>>(init_rel, w_rel, outr, relrows);
}

// Round 13
// 241.927 us; speedup vs baseline: 1.3554x; 1.0835x over previous
//
#include <hip/hip_runtime.h>
#include <hip/hip_bf16.h>

#define NENT 40000
#define NREL 20
#define DIM 128
#define NBASIS 8
#define TILE 32                // nodes per fused block
#define PKCAP 1024             // LDS-staged packed entries per tile (avg ~512)
#define SCANBLK 157            // ceil(40000/256)

typedef __attribute__((ext_vector_type(8))) short sh8;
typedef __attribute__((ext_vector_type(4))) float fx4;

__device__ __forceinline__ short f2bf(float f) {
    union { __hip_bfloat16 h; short s; } u;
    u.h = __float2bfloat16(f);
    return u.s;
}

// f32 -> bf16 copy (x panel for layer 1 + gather source)
__global__ void k_tobf(const float* __restrict__ x, ushort* __restrict__ xb, int nelem) {
    int i = (blockIdx.x * 256 + threadIdx.x) * 4;
    if (i >= nelem) return;
    float4 v = *(const float4*)(x + i);
    ushort4 o;
    o.x = (ushort)f2bf(v.x); o.y = (ushort)f2bf(v.y);
    o.z = (ushort)f2bf(v.z); o.w = (ushort)f2bf(v.w);
    *(ushort4*)(xb + i) = o;
}

// Fragment-order stacked B: ks 0..7 = basis[ks] (k-rows i), ks 8 = root.
// B-frag: lane holds B[k = kk*32 + lhi*8 + e][col = c*16 + l15].
__global__ void k_wfrag9(const float* __restrict__ basis, const float* __restrict__ root,
                         short* __restrict__ Wfb) {
    int t = blockIdx.x * 256 + threadIdx.x;
    if (t >= 9 * 16384) return;
    int ks = t / 16384;
    int rem = t & 16383;
    int i = rem >> 7, o = rem & 127;
    float v = (ks < 8) ? basis[ks * 16384 + i * 128 + o] : root[i * 128 + o];
    int c = o >> 4, l15 = o & 15;
    int kk = i >> 5, lhi = (i >> 3) & 3, e = i & 7;
    int lane = l15 + lhi * 16;
    Wfb[(size_t)ks * 16384 + (size_t)(((c * 4 + kk) * 64 + lane) << 3) + e] = f2bf(v);
}

__global__ void k_hist(const int* __restrict__ dst, int E, int* __restrict__ hist) {
    int e = blockIdx.x * 256 + threadIdx.x;
    if (e < E) atomicAdd(&hist[dst[e]], 1);
}

// -------- 3-phase parallel scan over NENT bins --------
__global__ void k_scan1(const int* __restrict__ hist, int* __restrict__ offs,
                        int* __restrict__ bsum) {
    __shared__ int ps[256];
    int t = threadIdx.x;
    int i = blockIdx.x * 256 + t;
    int v = (i < NENT) ? hist[i] : 0;
    ps[t] = v;
    __syncthreads();
    for (int off = 1; off < 256; off <<= 1) {
        int u = (t >= off) ? ps[t - off] : 0;
        __syncthreads();
        ps[t] += u;
        __syncthreads();
    }
    if (i < NENT) offs[i] = ps[t] - v;
    if (t == 255) bsum[blockIdx.x] = ps[255];
}

__global__ void k_scan2(int* __restrict__ bsum) {
    __shared__ int ps[256];
    int t = threadIdx.x;
    int v = (t < SCANBLK) ? bsum[t] : 0;
    ps[t] = v;
    __syncthreads();
    for (int off = 1; off < 256; off <<= 1) {
        int u = (t >= off) ? ps[t - off] : 0;
        __syncthreads();
        ps[t] += u;
        __syncthreads();
    }
    if (t < SCANBLK) bsum[t] = ps[t] - v;
}

__global__ void k_scan3(int* __restrict__ offs, int* __restrict__ cursor,
                        const int* __restrict__ bsum, int E) {
    int i = blockIdx.x * 256 + threadIdx.x;
    if (i < NENT) {
        int o = offs[i] + bsum[blockIdx.x];
        offs[i] = o;
        cursor[i] = o;
    }
    if (i == 0) offs[NENT] = E;
}

// counting-sort by dst: packed = src | et<<16
__global__ void k_scatter(const int* __restrict__ et, const int* __restrict__ srcA,
                          const int* __restrict__ dstA, int E,
                          int* __restrict__ cursor, unsigned* __restrict__ packed) {
    int e = blockIdx.x * 256 + threadIdx.x;
    if (e >= E) return;
    int pos = atomicAdd(&cursor[dstA[e]], 1);
    packed[pos] = (unsigned)srcA[e] | ((unsigned)et[e] << 16);
}

// pinned async load: dword per lane, dest physically held in a VGPR
#define GLDD(dst, ptr)                                                     \
    asm volatile("global_load_dword %0, %1, off" : "=v"(dst) : "v"(ptr))

#define WAITV(N)                                                           \
    do {                                                                   \
        asm volatile("s_waitcnt vmcnt(" #N ")" ::: "memory");              \
        __builtin_amdgcn_sched_barrier(0);                                 \
    } while (0)

// Fused RGCN layer: block = 32 dst nodes, 8 waves.
// Phase 1: packed staged in LDS; wave w gathers nodes w*4..w*4+3 in registers.
//   8-edge batches ping-pong with asm-pinned loads + counted vmcnt: exactly
//   8 loads always issued per batch (tail clamped to edge 0's row, L1-hot),
//   so vmcnt(8) before each proc guarantees the batch landed while the next
//   8 stay in flight. Drain vmcnt(0) before register reuse.
// Phase 2: C[32x128] = [G_lds(1024) | x(128)] @ Wfb + bias via MFMA.
__global__ __launch_bounds__(512) void k_fused(
    const ushort* __restrict__ xb, const unsigned* __restrict__ packed,
    const int* __restrict__ offs, const float* __restrict__ comp,
    const short* __restrict__ Wfb, const float* __restrict__ bias,
    ushort* __restrict__ outbf, float* __restrict__ outf, int act) {
    __shared__ __align__(16) ushort Gl[TILE * 1024];   // 64KB
    __shared__ __align__(16) float cl[NREL * NBASIS];
    __shared__ __align__(16) unsigned pkl[PKCAP];      // 4KB

    int t = threadIdx.x;
    int lane = t & 63, wid = t >> 6;
    if (t < NREL * NBASIS) cl[t] = comp[t];

    int tile0 = blockIdx.x * TILE;
    int base = offs[tile0];
    int totE = offs[tile0 + TILE] - base;
    for (int i = t; i < totE && i < PKCAP; i += 512) pkl[i] = packed[base + i];
    __syncthreads();

    // ---- phase 1: gather (4 nodes per wave, 8-deep pinned pipeline) ----
    const unsigned* xrow = (const unsigned*)xb + lane;
    bool fast = (totE <= PKCAP);
    for (int sub = 0; sub < 4; ++sub) {
        int row = wid * 4 + sub;             // 0..31
        int n = tile0 + row;
        int begg = offs[n];
        int cnt = offs[n + 1] - begg;
        int begl = begg - base;

        float a0[NBASIS], a1[NBASIS];
#pragma unroll
        for (int b = 0; b < NBASIS; ++b) { a0[b] = 0.f; a1[b] = 0.f; }

        if (cnt > 0 && fast) {
            unsigned p0v = pkl[begl];
            unsigned pA[8], pB[8], rA[8], rB[8];

            auto ldp = [&](int i0, unsigned (&p)[8]) {
#pragma unroll
                for (int u = 0; u < 8; ++u) {
                    int i = i0 + u;
                    p[u] = (i < cnt) ? pkl[begl + i] : p0v;   // clamp: L1-hot row
                }
            };
            auto issue = [&](const unsigned (&p)[8], unsigned (&r)[8]) {
#pragma unroll
                for (int u = 0; u < 8; ++u) {
                    const unsigned* ap = xrow + (size_t)(p[u] & 0xFFFFu) * 64;
                    GLDD(r[u], ap);
                }
            };
            auto proc = [&](int i0, const unsigned (&p)[8], const unsigned (&r)[8]) {
#pragma unroll
                for (int u = 0; u < 8; ++u) {
                    if (i0 + u < cnt) {      // wave-uniform
                        float xlo = __uint_as_float(r[u] << 16);
                        float xhi = __uint_as_float(r[u] & 0xFFFF0000u);
                        int et = p[u] >> 16;
                        float4 cwa = *(const float4*)&cl[et * NBASIS];
                        float4 cwb = *(const float4*)&cl[et * NBASIS + 4];
                        a0[0] += cwa.x * xlo; a1[0] += cwa.x * xhi;
                        a0[1] += cwa.y * xlo; a1[1] += cwa.y * xhi;
                        a0[2] += cwa.z * xlo; a1[2] += cwa.z * xhi;
                        a0[3] += cwa.w * xlo; a1[3] += cwa.w * xhi;
                        a0[4] += cwb.x * xlo; a1[4] += cwb.x * xhi;
                        a0[5] += cwb.y * xlo; a1[5] += cwb.y * xhi;
                        a0[6] += cwb.z * xlo; a1[6] += cwb.z * xhi;
                        a0[7] += cwb.w * xlo; a1[7] += cwb.w * xhi;
                    }
                }
            };

            ldp(0, pA); issue(pA, rA);           // 8 outstanding
            int i0 = 0;
            while (i0 < cnt) {
                ldp(i0 + 8, pB); issue(pB, rB);  // 16 outstanding
                WAITV(8);                        // batch A landed
                proc(i0, pA, rA);
                i0 += 8;
                if (i0 >= cnt) break;
                ldp(i0 + 8, pA); issue(pA, rA);  // 16 outstanding
                WAITV(8);                        // batch B landed
                proc(i0, pB, rB);
                i0 += 8;
            }
            asm volatile("s_waitcnt vmcnt(0)" ::: "memory");  // drain speculative
            __builtin_amdgcn_sched_barrier(0);
        } else if (cnt > 0) {
            // slow fallback (tile overflows PKCAP): depth-2 scalar pipeline
            unsigned pA = packed[begg], pB = 0, rA = xrow[(size_t)(pA & 0xFFFFu) * 64];
            if (cnt > 1) pB = packed[begg + 1];
            for (int i = 0; i < cnt; ++i) {
                unsigned pC = (i + 2 < cnt) ? packed[begg + i + 2] : 0u;
                unsigned rB = xrow[(size_t)(pB & 0xFFFFu) * 64];
                float xlo = __uint_as_float(rA << 16);
                float xhi = __uint_as_float(rA & 0xFFFF0000u);
                int et = pA >> 16;
                float4 cwa = *(const float4*)&cl[et * NBASIS];
                float4 cwb = *(const float4*)&cl[et * NBASIS + 4];
                a0[0] += cwa.x * xlo; a1[0] += cwa.x * xhi;
                a0[1] += cwa.y * xlo; a1[1] += cwa.y * xhi;
                a0[2] += cwa.z * xlo; a1[2] += cwa.z * xhi;
                a0[3] += cwa.w * xlo; a1[3] += cwa.w * xhi;
                a0[4] += cwb.x * xlo; a1[4] += cwb.x * xhi;
                a0[5] += cwb.y * xlo; a1[5] += cwb.y * xhi;
                a0[6] += cwb.z * xlo; a1[6] += cwb.z * xhi;
                a0[7] += cwb.w * xlo; a1[7] += cwb.w * xhi;
                pA = pB; pB = pC; rA = rB;
            }
        }

        float inv = 1.f / (float)(cnt < 1 ? 1 : cnt);
#pragma unroll
        for (int b = 0; b < NBASIS; ++b) {
            unsigned lo = (unsigned)(ushort)f2bf(a0[b] * inv);
            unsigned hi = (unsigned)(ushort)f2bf(a1[b] * inv);
            unsigned byteoff = (unsigned)(row * 2048 + b * 256 + lane * 4);
            byteoff ^= (unsigned)((row & 7) << 4);   // bank swizzle
            *(unsigned*)((char*)Gl + byteoff) = lo | (hi << 16);
        }
    }
    __syncthreads();

    // ---- phase 2: MFMA GEMM ----
    int wr = wid >> 2, wc = wid & 3;          // 2 row-groups x 4 col-groups
    int l15 = lane & 15, lhi = lane >> 4;
    int arow = wr * 16 + l15;                 // LDS row this lane reads

    fx4 acc0 = (fx4){0.f, 0.f, 0.f, 0.f};
    fx4 acc1 = (fx4){0.f, 0.f, 0.f, 0.f};

    const ushort* Xr = xb + (size_t)(tile0 + wr * 16 + l15) * 128 + lhi * 8;
    const sh8* W8 = (const sh8*)Wfb;
    int c0 = wc * 2, c1 = wc * 2 + 1;

#pragma unroll
    for (int ks = 0; ks < 9; ++ks) {
        sh8 a[4];
        if (ks < 8) {
#pragma unroll
            for (int kk = 0; kk < 4; ++kk) {
                unsigned byteoff = (unsigned)(arow * 2048 + ks * 256 + kk * 64 + lhi * 16);
                byteoff ^= (unsigned)((arow & 7) << 4);
                a[kk] = *(const sh8*)((const char*)Gl + byteoff);
            }
        } else {
#pragma unroll
            for (int kk = 0; kk < 4; ++kk) a[kk] = *(const sh8*)(Xr + kk * 32);
        }
#pragma unroll
        for (int kk = 0; kk < 4; ++kk) {
            sh8 b0 = W8[(size_t)ks * 2048 + (size_t)((c0 * 4 + kk) * 64 + lane)];
            sh8 b1 = W8[(size_t)ks * 2048 + (size_t)((c1 * 4 + kk) * 64 + lane)];
            acc0 = __builtin_amdgcn_mfma_f32_16x16x32_bf16(a[kk], b0, acc0, 0, 0, 0);
            acc1 = __builtin_amdgcn_mfma_f32_16x16x32_bf16(a[kk], b1, acc1, 0, 0, 0);
        }
    }

    // bias + act + store
    int orow0 = tile0 + wr * 16 + lhi * 4;
#pragma unroll
    for (int cc = 0; cc < 2; ++cc) {
        int col = wc * 32 + cc * 16 + l15;
        float bv = bias[col];
        const fx4& ac = cc ? acc1 : acc0;
#pragma unroll
        for (int j = 0; j < 4; ++j) {
            float v = ac[j] + bv;
            if (act) {
                v = tanhf(v);
                outbf[(size_t)(orow0 + j) * 128 + col] = (ushort)f2bf(v);
            } else {
                outf[(size_t)(orow0 + j) * 128 + col] = v;
            }
        }
    }
}

__global__ void k_rel(const float* __restrict__ rel, const float* __restrict__ wrel,
                      float* __restrict__ out, int nrows) {
    int idx = blockIdx.x * 256 + threadIdx.x;
    if (idx >= nrows * DIM) return;
    int j = idx >> 7, o = idx & 127;
    float s = 0.f;
    for (int i = 0; i < DIM; ++i) s += rel[j * DIM + i] * wrel[i * DIM + o];
    out[idx] = s;
}

extern "C" void kernel_launch(void* const* d_in, const int* in_sizes, int n_in,
                              void* d_out, int out_size, void* d_ws, size_t ws_size,
                              hipStream_t stream) {
    const int* edge_index = (const int*)d_in[0];
    const int* edge_type  = (const int*)d_in[1];
    const float* init_embed = (const float*)d_in[2];
    const float* init_rel   = (const float*)d_in[3];
    const float* w_rel      = (const float*)d_in[4];
    const float* comp1  = (const float*)d_in[5];
    const float* basis1 = (const float*)d_in[6];
    const float* root1  = (const float*)d_in[7];
    const float* bias1  = (const float*)d_in[8];
    const float* comp2  = (const float*)d_in[9];
    const float* basis2 = (const float*)d_in[10];
    const float* root2  = (const float*)d_in[11];
    const float* bias2  = (const float*)d_in[12];

    int E = in_sizes[1];
    const int* src = edge_index;
    const int* dst = edge_index + E;
    int relrows = in_sizes[3] / DIM;   // 40

    // workspace layout (16B-aligned regions)
    short* Wfb1 = (short*)d_ws;                          // 9*16384 shorts
    short* Wfb2 = Wfb1 + (size_t)9 * 16384;
    ushort* xb  = (ushort*)(Wfb2 + (size_t)9 * 16384);   // 40000*128 bf16
    ushort* hb  = xb + (size_t)NENT * DIM;               // 40000*128 bf16
    int* hist   = (int*)(hb + (size_t)NENT * DIM);       // 40000 (pad 40004)
    int* offs   = hist + 40004;
    int* cursor = offs + 40004;
    int* bsum   = cursor + 40004;                        // 157 (pad 160)
    unsigned* packed = (unsigned*)(bsum + 160);          // E

    float* outx = (float*)d_out;
    float* outr = outx + (size_t)NENT * DIM;

    hipMemsetAsync(hist, 0, NENT * sizeof(int), stream);

    k_tobf<<<(NENT * DIM / 4 + 255) / 256, 256, 0, stream>>>(init_embed, xb, NENT * DIM);
    k_wfrag9<<<(9 * 16384 + 255) / 256, 256, 0, stream>>>(basis1, root1, Wfb1);
    k_wfrag9<<<(9 * 16384 + 255) / 256, 256, 0, stream>>>(basis2, root2, Wfb2);
    k_hist<<<(E + 255) / 256, 256, 0, stream>>>(dst, E, hist);
    k_scan1<<<SCANBLK, 256, 0, stream>>>(hist, offs, bsum);
    k_scan2<<<1, 256, 0, stream>>>(bsum);
    k_scan3<<<SCANBLK, 256, 0, stream>>>(offs, cursor, bsum, E);
    k_scatter<<<(E + 255) / 256, 256, 0, stream>>>(edge_type, src, dst, E, cursor, packed);

    // layer 1: hb = bf16(tanh(gather@W~1 + x@root1 + bias1))
    k_fused<<<NENT / TILE, 512, 0, stream>>>(xb, packed, offs, comp1, Wfb1, bias1,
                                             hb, outx, 1);
    // layer 2: out = gather@W~2 + h@root2 + bias2 (f32 to d_out)
    k_fused<<<NENT / TILE, 512, 0, stream>>>(hb, packed, offs, comp2, Wfb2, bias2,
                                             hb, outx, 0);

    // relation output: r = init_rel @ w_rel
    k_rel<<<(relrows * DIM + 255) / 256, 256, 0, stream>>>(init_rel, w_rel, outr, relrows);
}

// Round 14
// 229.662 us; speedup vs baseline: 1.4278x; 1.0534x over previous
//
#include <hip/hip_runtime.h>
#include <hip/hip_bf16.h>

#define NENT 40000
#define NREL 20
#define DIM 128
#define NBASIS 8
#define TILE 32                // nodes per fused block
#define PKCAP 1024             // LDS-staged packed entries per tile (avg ~512)
#define SCANBLK 157            // ceil(40000/256)

typedef __attribute__((ext_vector_type(8))) short sh8;
typedef __attribute__((ext_vector_type(4))) float fx4;

__device__ __forceinline__ short f2bf(float f) {
    union { __hip_bfloat16 h; short s; } u;
    u.h = __float2bfloat16(f);
    return u.s;
}

// f32 -> bf16 copy (x panel for layer 1 + gather source)
__global__ void k_tobf(const float* __restrict__ x, ushort* __restrict__ xb, int nelem) {
    int i = (blockIdx.x * 256 + threadIdx.x) * 4;
    if (i >= nelem) return;
    float4 v = *(const float4*)(x + i);
    ushort4 o;
    o.x = (ushort)f2bf(v.x); o.y = (ushort)f2bf(v.y);
    o.z = (ushort)f2bf(v.z); o.w = (ushort)f2bf(v.w);
    *(ushort4*)(xb + i) = o;
}

// Fragment-order stacked B: ks 0..7 = basis[ks] (k-rows i), ks 8 = root.
// B-frag: lane holds B[k = kk*32 + lhi*8 + e][col = c*16 + l15].
__global__ void k_wfrag9(const float* __restrict__ basis, const float* __restrict__ root,
                         short* __restrict__ Wfb) {
    int t = blockIdx.x * 256 + threadIdx.x;
    if (t >= 9 * 16384) return;
    int ks = t / 16384;
    int rem = t & 16383;
    int i = rem >> 7, o = rem & 127;
    float v = (ks < 8) ? basis[ks * 16384 + i * 128 + o] : root[i * 128 + o];
    int c = o >> 4, l15 = o & 15;
    int kk = i >> 5, lhi = (i >> 3) & 3, e = i & 7;
    int lane = l15 + lhi * 16;
    Wfb[(size_t)ks * 16384 + (size_t)(((c * 4 + kk) * 64 + lane) << 3) + e] = f2bf(v);
}

__global__ void k_hist(const int* __restrict__ dst, int E, int* __restrict__ hist) {
    int e = blockIdx.x * 256 + threadIdx.x;
    if (e < E) atomicAdd(&hist[dst[e]], 1);
}

// -------- 3-phase parallel scan over NENT bins --------
__global__ void k_scan1(const int* __restrict__ hist, int* __restrict__ offs,
                        int* __restrict__ bsum) {
    __shared__ int ps[256];
    int t = threadIdx.x;
    int i = blockIdx.x * 256 + t;
    int v = (i < NENT) ? hist[i] : 0;
    ps[t] = v;
    __syncthreads();
    for (int off = 1; off < 256; off <<= 1) {
        int u = (t >= off) ? ps[t - off] : 0;
        __syncthreads();
        ps[t] += u;
        __syncthreads();
    }
    if (i < NENT) offs[i] = ps[t] - v;
    if (t == 255) bsum[blockIdx.x] = ps[255];
}

__global__ void k_scan2(int* __restrict__ bsum) {
    __shared__ int ps[256];
    int t = threadIdx.x;
    int v = (t < SCANBLK) ? bsum[t] : 0;
    ps[t] = v;
    __syncthreads();
    for (int off = 1; off < 256; off <<= 1) {
        int u = (t >= off) ? ps[t - off] : 0;
        __syncthreads();
        ps[t] += u;
        __syncthreads();
    }
    if (t < SCANBLK) bsum[t] = ps[t] - v;
}

__global__ void k_scan3(int* __restrict__ offs, int* __restrict__ cursor,
                        const int* __restrict__ bsum, int E) {
    int i = blockIdx.x * 256 + threadIdx.x;
    if (i < NENT) {
        int o = offs[i] + bsum[blockIdx.x];
        offs[i] = o;
        cursor[i] = o;
    }
    if (i == 0) offs[NENT] = E;
}

// counting-sort by dst: packed = src | et<<16
__global__ void k_scatter(const int* __restrict__ et, const int* __restrict__ srcA,
                          const int* __restrict__ dstA, int E,
                          int* __restrict__ cursor, unsigned* __restrict__ packed) {
    int e = blockIdx.x * 256 + threadIdx.x;
    if (e >= E) return;
    int pos = atomicAdd(&cursor[dstA[e]], 1);
    packed[pos] = (unsigned)srcA[e] | ((unsigned)et[e] << 16);
}

// pinned async load, saddr form: scalar 64-bit base + per-lane 32-bit offset
#define GLDS(dst, voff, sbase)                                             \
    asm volatile("global_load_dword %0, %1, %2"                            \
                 : "=v"(dst) : "v"(voff), "s"(sbase))

#define WAITV(N)                                                           \
    do {                                                                   \
        asm volatile("s_waitcnt vmcnt(" #N ")" ::: "memory");              \
        __builtin_amdgcn_sched_barrier(0);                                 \
    } while (0)

// Fused RGCN layer: block = 32 dst nodes, 8 waves.
// Phase 1: per-edge metadata on the SCALAR pipe (readfirstlane of LDS-staged
//   packed; comp via scalar-cache float4 loads from global); x-row loads via
//   saddr-form pinned asm, 8-deep ping-pong with counted vmcnt. Per-edge
//   vector cost = 2 unpack + 16 FMA; per-edge LDS = one b32 broadcast.
// Phase 2: C[32x128] = [G_lds(1024) | x(128)] @ Wfb + bias via MFMA;
//   8 waves = 8 col-groups x 32 rows (no redundant B-frag loads).
__global__ __launch_bounds__(512) void k_fused(
    const ushort* __restrict__ xb, const unsigned* __restrict__ packed,
    const int* __restrict__ offs, const float* __restrict__ comp,
    const short* __restrict__ Wfb, const float* __restrict__ bias,
    ushort* __restrict__ outbf, float* __restrict__ outf, int act) {
    __shared__ __align__(16) ushort Gl[TILE * 1024];   // 64KB
    __shared__ __align__(16) unsigned pkl[PKCAP];      // 4KB

    int t = threadIdx.x;
    int lane = t & 63, wid = t >> 6;
    unsigned lane4 = (unsigned)(lane * 4);

    int tile0 = blockIdx.x * TILE;
    int base = offs[tile0];
    int totE = offs[tile0 + TILE] - base;
    for (int i = t; i < totE && i < PKCAP; i += 512) pkl[i] = packed[base + i];
    __syncthreads();

    // ---- phase 1: gather (4 nodes per wave, scalar-metadata pipeline) ----
    bool fast = (totE <= PKCAP);
    for (int sub = 0; sub < 4; ++sub) {
        int row = wid * 4 + sub;             // 0..31
        int n = tile0 + row;
        int begg = offs[n];
        int cnt = offs[n + 1] - begg;
        int begl = begg - base;

        float a0[NBASIS], a1[NBASIS];
#pragma unroll
        for (int b = 0; b < NBASIS; ++b) { a0[b] = 0.f; a1[b] = 0.f; }

        if (cnt > 0 && fast) {
            int sbA[8], seA[8], sbB[8], seB[8];
            unsigned rA[8], rB[8];

            auto ldp = [&](int i0, int (&sb)[8], int (&se)[8]) {
#pragma unroll
                for (int u = 0; u < 8; ++u) {
                    int i = i0 + u;
                    int li = begl + (i < cnt ? i : 0);   // clamp: L1-hot row
                    unsigned p = __builtin_amdgcn_readfirstlane(pkl[li]);
                    sb[u] = (int)(p & 0xFFFFu) * 256;    // scalar byte offset
                    se[u] = (int)(p >> 16);
                }
            };
            auto issue = [&](const int (&sb)[8], unsigned (&r)[8]) {
#pragma unroll
                for (int u = 0; u < 8; ++u) {
                    const char* bp = (const char*)xb + sb[u];   // uniform base
                    GLDS(r[u], lane4, bp);
                }
            };
            auto proc = [&](int i0, const int (&se)[8], const unsigned (&r)[8]) {
#pragma unroll
                for (int u = 0; u < 8; ++u) {
                    if (i0 + u < cnt) {      // wave-uniform
                        const float4* cp = (const float4*)(comp + se[u] * NBASIS);
                        float4 cwa = cp[0];  // scalar-cache loads
                        float4 cwb = cp[1];
                        float xlo = __uint_as_float(r[u] << 16);
                        float xhi = __uint_as_float(r[u] & 0xFFFF0000u);
                        a0[0] += cwa.x * xlo; a1[0] += cwa.x * xhi;
                        a0[1] += cwa.y * xlo; a1[1] += cwa.y * xhi;
                        a0[2] += cwa.z * xlo; a1[2] += cwa.z * xhi;
                        a0[3] += cwa.w * xlo; a1[3] += cwa.w * xhi;
                        a0[4] += cwb.x * xlo; a1[4] += cwb.x * xhi;
                        a0[5] += cwb.y * xlo; a1[5] += cwb.y * xhi;
                        a0[6] += cwb.z * xlo; a1[6] += cwb.z * xhi;
                        a0[7] += cwb.w * xlo; a1[7] += cwb.w * xhi;
                    }
                }
            };

            ldp(0, sbA, seA); issue(sbA, rA);            // 8 outstanding
            int i0 = 0;
            while (i0 < cnt) {
                ldp(i0 + 8, sbB, seB); issue(sbB, rB);   // 16 outstanding
                WAITV(8);                                // batch A landed
                proc(i0, seA, rA);
                i0 += 8;
                if (i0 >= cnt) break;
                ldp(i0 + 8, sbA, seA); issue(sbA, rA);
                WAITV(8);                                // batch B landed
                proc(i0, seB, rB);
                i0 += 8;
            }
            asm volatile("s_waitcnt vmcnt(0)" ::: "memory");  // drain speculative
            __builtin_amdgcn_sched_barrier(0);
        } else if (cnt > 0) {
            // slow fallback (tile overflows PKCAP): depth-2 scalar pipeline
            const unsigned* xrow = (const unsigned*)xb + lane;
            unsigned pA = packed[begg], pB = 0, rA = xrow[(size_t)(pA & 0xFFFFu) * 64];
            if (cnt > 1) pB = packed[begg + 1];
            for (int i = 0; i < cnt; ++i) {
                unsigned pC = (i + 2 < cnt) ? packed[begg + i + 2] : 0u;
                unsigned rB = xrow[(size_t)(pB & 0xFFFFu) * 64];
                float xlo = __uint_as_float(rA << 16);
                float xhi = __uint_as_float(rA & 0xFFFF0000u);
                int et = pA >> 16;
                const float4* cp = (const float4*)(comp + et * NBASIS);
                float4 cwa = cp[0];
                float4 cwb = cp[1];
                a0[0] += cwa.x * xlo; a1[0] += cwa.x * xhi;
                a0[1] += cwa.y * xlo; a1[1] += cwa.y * xhi;
                a0[2] += cwa.z * xlo; a1[2] += cwa.z * xhi;
                a0[3] += cwa.w * xlo; a1[3] += cwa.w * xhi;
                a0[4] += cwb.x * xlo; a1[4] += cwb.x * xhi;
                a0[5] += cwb.y * xlo; a1[5] += cwb.y * xhi;
                a0[6] += cwb.z * xlo; a1[6] += cwb.z * xhi;
                a0[7] += cwb.w * xlo; a1[7] += cwb.w * xhi;
                pA = pB; pB = pC; rA = rB;
            }
        }

        float inv = 1.f / (float)(cnt < 1 ? 1 : cnt);
#pragma unroll
        for (int b = 0; b < NBASIS; ++b) {
            unsigned lo = (unsigned)(ushort)f2bf(a0[b] * inv);
            unsigned hi = (unsigned)(ushort)f2bf(a1[b] * inv);
            unsigned byteoff = (unsigned)(row * 2048 + b * 256 + lane * 4);
            byteoff ^= (unsigned)((row & 7) << 4);   // bank swizzle
            *(unsigned*)((char*)Gl + byteoff) = lo | (hi << 16);
        }
    }
    __syncthreads();

    // ---- phase 2: MFMA GEMM (wave = one 16-col group x all 32 rows) ----
    int l15 = lane & 15, lhi = lane >> 4;
    int c = wid;                              // col-group 0..7

    fx4 acc0 = (fx4){0.f, 0.f, 0.f, 0.f};    // rows 0..15
    fx4 acc1 = (fx4){0.f, 0.f, 0.f, 0.f};    // rows 16..31

    const sh8* W8 = (const sh8*)Wfb;

#pragma unroll
    for (int ks = 0; ks < 9; ++ks) {
        sh8 a0f[4], a1f[4];
        if (ks < 8) {
#pragma unroll
            for (int kk = 0; kk < 4; ++kk) {
                int ar0 = l15, ar1 = 16 + l15;
                unsigned bo0 = (unsigned)(ar0 * 2048 + ks * 256 + kk * 64 + lhi * 16);
                unsigned bo1 = (unsigned)(ar1 * 2048 + ks * 256 + kk * 64 + lhi * 16);
                bo0 ^= (unsigned)((ar0 & 7) << 4);
                bo1 ^= (unsigned)((ar1 & 7) << 4);
                a0f[kk] = *(const sh8*)((const char*)Gl + bo0);
                a1f[kk] = *(const sh8*)((const char*)Gl + bo1);
            }
        } else {
#pragma unroll
            for (int kk = 0; kk < 4; ++kk) {
                a0f[kk] = *(const sh8*)(xb + (size_t)(tile0 + l15) * 128 + lhi * 8 + kk * 32);
                a1f[kk] = *(const sh8*)(xb + (size_t)(tile0 + 16 + l15) * 128 + lhi * 8 + kk * 32);
            }
        }
#pragma unroll
        for (int kk = 0; kk < 4; ++kk) {
            sh8 b = W8[(size_t)ks * 2048 + (size_t)((c * 4 + kk) * 64 + lane)];
            acc0 = __builtin_amdgcn_mfma_f32_16x16x32_bf16(a0f[kk], b, acc0, 0, 0, 0);
            acc1 = __builtin_amdgcn_mfma_f32_16x16x32_bf16(a1f[kk], b, acc1, 0, 0, 0);
        }
    }

    // bias + act + store
    int col = c * 16 + l15;
    float bv = bias[col];
#pragma unroll
    for (int rg = 0; rg < 2; ++rg) {
        const fx4& ac = rg ? acc1 : acc0;
        int orow0 = tile0 + rg * 16 + lhi * 4;
#pragma unroll
        for (int j = 0; j < 4; ++j) {
            float v = ac[j] + bv;
            if (act) {
                v = tanhf(v);
                outbf[(size_t)(orow0 + j) * 128 + col] = (ushort)f2bf(v);
            } else {
                outf[(size_t)(orow0 + j) * 128 + col] = v;
            }
        }
    }
}

__global__ void k_rel(const float* __restrict__ rel, const float* __restrict__ wrel,
                      float* __restrict__ out, int nrows) {
    int idx = blockIdx.x * 256 + threadIdx.x;
    if (idx >= nrows * DIM) return;
    int j = idx >> 7, o = idx & 127;
    float s = 0.f;
    for (int i = 0; i < DIM; ++i) s += rel[j * DIM + i] * wrel[i * DIM + o];
    out[idx] = s;
}

extern "C" void kernel_launch(void* const* d_in, const int* in_sizes, int n_in,
                              void* d_out, int out_size, void* d_ws, size_t ws_size,
                              hipStream_t stream) {
    const int* edge_index = (const int*)d_in[0];
    const int* edge_type  = (const int*)d_in[1];
    const float* init_embed = (const float*)d_in[2];
    const float* init_rel   = (const float*)d_in[3];
    const float* w_rel      = (const float*)d_in[4];
    const float* comp1  = (const float*)d_in[5];
    const float* basis1 = (const float*)d_in[6];
    const float* root1  = (const float*)d_in[7];
    const float* bias1  = (const float*)d_in[8];
    const float* comp2  = (const float*)d_in[9];
    const float* basis2 = (const float*)d_in[10];
    const float* root2  = (const float*)d_in[11];
    const float* bias2  = (const float*)d_in[12];

    int E = in_sizes[1];
    const int* src = edge_index;
    const int* dst = edge_index + E;
    int relrows = in_sizes[3] / DIM;   // 40

    // workspace layout (16B-aligned regions)
    short* Wfb1 = (short*)d_ws;                          // 9*16384 shorts
    short* Wfb2 = Wfb1 + (size_t)9 * 16384;
    ushort* xb  = (ushort*)(Wfb2 + (size_t)9 * 16384);   // 40000*128 bf16
    ushort* hb  = xb + (size_t)NENT * DIM;               // 40000*128 bf16
    int* hist   = (int*)(hb + (size_t)NENT * DIM);       // 40000 (pad 40004)
    int* offs   = hist + 40004;
    int* cursor = offs + 40004;
    int* bsum   = cursor + 40004;                        // 157 (pad 160)
    unsigned* packed = (unsigned*)(bsum + 160);          // E

    float* outx = (float*)d_out;
    float* outr = outx + (size_t)NENT * DIM;

    hipMemsetAsync(hist, 0, NENT * sizeof(int), stream);

    k_tobf<<<(NENT * DIM / 4 + 255) / 256, 256, 0, stream>>>(init_embed, xb, NENT * DIM);
    k_wfrag9<<<(9 * 16384 + 255) / 256, 256, 0, stream>>>(basis1, root1, Wfb1);
    k_wfrag9<<<(9 * 16384 + 255) / 256, 256, 0, stream>>>(basis2, root2, Wfb2);
    k_hist<<<(E + 255) / 256, 256, 0, stream>>>(dst, E, hist);
    k_scan1<<<SCANBLK, 256, 0, stream>>>(hist, offs, bsum);
    k_scan2<<<1, 256, 0, stream>>>(bsum);
    k_scan3<<<SCANBLK, 256, 0, stream>>>(offs, cursor, bsum, E);
    k_scatter<<<(E + 255) / 256, 256, 0, stream>>>(edge_type, src, dst, E, cursor, packed);

    // layer 1: hb = bf16(tanh(gather@W~1 + x@root1 + bias1))
    k_fused<<<NENT / TILE, 512, 0, stream>>>(xb, packed, offs, comp1, Wfb1, bias1,
                                             hb, outx, 1);
    // layer 2: out = gather@W~2 + h@root2 + bias2 (f32 to d_out)
    k_fused<<<NENT / TILE, 512, 0, stream>>>(hb, packed, offs, comp2, Wfb2, bias2,
                                             hb, outx, 0);

    // relation output: r = init_rel @ w_rel
    k_rel<<<(relrows * DIM + 255) / 256, 256, 0, stream>>>(init_rel, w_rel, outr, relrows);
}

// Round 17
// 228.134 us; speedup vs baseline: 1.4373x; 1.0067x over previous
//
#include <hip/hip_runtime.h>
#include <hip/hip_bf16.h>

#define NENT 40000
#define NREL 20
#define DIM 128
#define NBASIS 8
#define TILE 16                // nodes per fused block (32KB G tile -> 4 blocks/CU)
#define PKCAP 512              // LDS-staged packed entries per tile (avg ~256)
#define SCANBLK 157            // ceil(40000/256)

typedef __attribute__((ext_vector_type(8))) short sh8;
typedef __attribute__((ext_vector_type(4))) float fx4;

__device__ __forceinline__ short f2bf(float f) {
    union { __hip_bfloat16 h; short s; } u;
    u.h = __float2bfloat16(f);
    return u.s;
}

// f32 -> bf16 copy (x panel for layer 1 + gather source)
__global__ void k_tobf(const float* __restrict__ x, ushort* __restrict__ xb, int nelem) {
    int i = (blockIdx.x * 256 + threadIdx.x) * 4;
    if (i >= nelem) return;
    float4 v = *(const float4*)(x + i);
    ushort4 o;
    o.x = (ushort)f2bf(v.x); o.y = (ushort)f2bf(v.y);
    o.z = (ushort)f2bf(v.z); o.w = (ushort)f2bf(v.w);
    *(ushort4*)(xb + i) = o;
}

// Fragment-order stacked B: ks 0..7 = basis[ks] (k-rows i), ks 8 = root.
__global__ void k_wfrag9(const float* __restrict__ basis, const float* __restrict__ root,
                         short* __restrict__ Wfb) {
    int t = blockIdx.x * 256 + threadIdx.x;
    if (t >= 9 * 16384) return;
    int ks = t / 16384;
    int rem = t & 16383;
    int i = rem >> 7, o = rem & 127;
    float v = (ks < 8) ? basis[ks * 16384 + i * 128 + o] : root[i * 128 + o];
    int c = o >> 4, l15 = o & 15;
    int kk = i >> 5, lhi = (i >> 3) & 3, e = i & 7;
    int lane = l15 + lhi * 16;
    Wfb[(size_t)ks * 16384 + (size_t)(((c * 4 + kk) * 64 + lane) << 3) + e] = f2bf(v);
}

__global__ void k_hist(const int* __restrict__ dst, int E, int* __restrict__ hist) {
    int e = blockIdx.x * 256 + threadIdx.x;
    if (e < E) atomicAdd(&hist[dst[e]], 1);
}

// -------- 3-phase parallel scan over NENT bins --------
__global__ void k_scan1(const int* __restrict__ hist, int* __restrict__ offs,
                        int* __restrict__ bsum) {
    __shared__ int ps[256];
    int t = threadIdx.x;
    int i = blockIdx.x * 256 + t;
    int v = (i < NENT) ? hist[i] : 0;
    ps[t] = v;
    __syncthreads();
    for (int off = 1; off < 256; off <<= 1) {
        int u = (t >= off) ? ps[t - off] : 0;
        __syncthreads();
        ps[t] += u;
        __syncthreads();
    }
    if (i < NENT) offs[i] = ps[t] - v;
    if (t == 255) bsum[blockIdx.x] = ps[255];
}

__global__ void k_scan2(int* __restrict__ bsum) {
    __shared__ int ps[256];
    int t = threadIdx.x;
    int v = (t < SCANBLK) ? bsum[t] : 0;
    ps[t] = v;
    __syncthreads();
    for (int off = 1; off < 256; off <<= 1) {
        int u = (t >= off) ? ps[t - off] : 0;
        __syncthreads();
        ps[t] += u;
        __syncthreads();
    }
    if (t < SCANBLK) bsum[t] = ps[t] - v;
}

__global__ void k_scan3(int* __restrict__ offs, int* __restrict__ cursor,
                        const int* __restrict__ bsum, int E) {
    int i = blockIdx.x * 256 + threadIdx.x;
    if (i < NENT) {
        int o = offs[i] + bsum[blockIdx.x];
        offs[i] = o;
        cursor[i] = o;
    }
    if (i == 0) offs[NENT] = E;
}

// counting-sort by dst: packed = src | et<<16
__global__ void k_scatter(const int* __restrict__ et, const int* __restrict__ srcA,
                          const int* __restrict__ dstA, int E,
                          int* __restrict__ cursor, unsigned* __restrict__ packed) {
    int e = blockIdx.x * 256 + threadIdx.x;
    if (e >= E) return;
    int pos = atomicAdd(&cursor[dstA[e]], 1);
    packed[pos] = (unsigned)srcA[e] | ((unsigned)et[e] << 16);
}

// pinned async load, saddr form: scalar 64-bit base + per-lane 32-bit offset
#define GLDS(dst, voff, sbase)                                             \
    asm volatile("global_load_dword %0, %1, %2"                            \
                 : "=v"(dst) : "v"(voff), "s"(sbase))

#define WAITV(N)                                                           \
    do {                                                                   \
        asm volatile("s_waitcnt vmcnt(" #N ")" ::: "memory");              \
        __builtin_amdgcn_sched_barrier(0);                                 \
    } while (0)

// Fused RGCN layer: block = 16 dst nodes, 8 waves, wave = 2 nodes.
// (Exact R14 per-node gather pipeline; only tile geometry changed so that
//  LDS = ~35KB -> 4 blocks/CU -> 32 waves/CU for gather latency hiding.)
// Phase 1: per-edge metadata on the scalar pipe (readfirstlane of LDS-staged
//   packed; comp via scalar-cache float4 loads); x-row loads via saddr-form
//   pinned asm, 8-deep ping-pong with counted vmcnt.
// Phase 2: C[16x128] = [G_lds(1024) | x(128)] @ Wfb + bias via MFMA;
//   8 waves = 8 col-groups x 16 rows.
__global__ __launch_bounds__(512) void k_fused(
    const ushort* __restrict__ xb, const unsigned* __restrict__ packed,
    const int* __restrict__ offs, const float* __restrict__ comp,
    const short* __restrict__ Wfb, const float* __restrict__ bias,
    ushort* __restrict__ outbf, float* __restrict__ outf, int act) {
    __shared__ __align__(16) ushort Gl[TILE * 1024];   // 32KB
    __shared__ __align__(16) unsigned pkl[PKCAP];      // 2KB

    int t = threadIdx.x;
    int lane = t & 63, wid = t >> 6;
    unsigned lane4 = (unsigned)(lane * 4);

    int tile0 = blockIdx.x * TILE;
    int base = offs[tile0];
    int totE = offs[tile0 + TILE] - base;
    for (int i = t; i < totE && i < PKCAP; i += 512) pkl[i] = packed[base + i];
    __syncthreads();

    // ---- phase 1: gather (2 nodes per wave, scalar-metadata pipeline) ----
    bool fast = (totE <= PKCAP);
    for (int sub = 0; sub < 2; ++sub) {
        int row = wid * 2 + sub;             // 0..15
        int n = tile0 + row;
        int begg = offs[n];
        int cnt = offs[n + 1] - begg;
        int begl = begg - base;

        float a0[NBASIS], a1[NBASIS];
#pragma unroll
        for (int b = 0; b < NBASIS; ++b) { a0[b] = 0.f; a1[b] = 0.f; }

        if (cnt > 0 && fast) {
            int sbA[8], seA[8], sbB[8], seB[8];
            unsigned rA[8], rB[8];

            auto ldp = [&](int i0, int (&sb)[8], int (&se)[8]) {
#pragma unroll
                for (int u = 0; u < 8; ++u) {
                    int i = i0 + u;
                    int li = begl + (i < cnt ? i : 0);   // clamp: L1-hot row
                    unsigned p = __builtin_amdgcn_readfirstlane(pkl[li]);
                    sb[u] = (int)(p & 0xFFFFu) * 256;    // scalar byte offset
                    se[u] = (int)(p >> 16);
                }
            };
            auto issue = [&](const int (&sb)[8], unsigned (&r)[8]) {
#pragma unroll
                for (int u = 0; u < 8; ++u) {
                    const char* bp = (const char*)xb + sb[u];   // uniform base
                    GLDS(r[u], lane4, bp);
                }
            };
            auto proc = [&](int i0, const int (&se)[8], const unsigned (&r)[8]) {
#pragma unroll
                for (int u = 0; u < 8; ++u) {
                    if (i0 + u < cnt) {      // wave-uniform
                        const float4* cp = (const float4*)(comp + se[u] * NBASIS);
                        float4 cwa = cp[0];  // scalar-cache loads
                        float4 cwb = cp[1];
                        float xlo = __uint_as_float(r[u] << 16);
                        float xhi = __uint_as_float(r[u] & 0xFFFF0000u);
                        a0[0] += cwa.x * xlo; a1[0] += cwa.x * xhi;
                        a0[1] += cwa.y * xlo; a1[1] += cwa.y * xhi;
                        a0[2] += cwa.z * xlo; a1[2] += cwa.z * xhi;
                        a0[3] += cwa.w * xlo; a1[3] += cwa.w * xhi;
                        a0[4] += cwb.x * xlo; a1[4] += cwb.x * xhi;
                        a0[5] += cwb.y * xlo; a1[5] += cwb.y * xhi;
                        a0[6] += cwb.z * xlo; a1[6] += cwb.z * xhi;
                        a0[7] += cwb.w * xlo; a1[7] += cwb.w * xhi;
                    }
                }
            };

            ldp(0, sbA, seA); issue(sbA, rA);            // 8 outstanding
            int i0 = 0;
            while (i0 < cnt) {
                ldp(i0 + 8, sbB, seB); issue(sbB, rB);   // 16 outstanding
                WAITV(8);                                // batch A landed
                proc(i0, seA, rA);
                i0 += 8;
                if (i0 >= cnt) break;
                ldp(i0 + 8, sbA, seA); issue(sbA, rA);
                WAITV(8);                                // batch B landed
                proc(i0, seB, rB);
                i0 += 8;
            }
            asm volatile("s_waitcnt vmcnt(0)" ::: "memory");  // drain speculative
            __builtin_amdgcn_sched_barrier(0);
        } else if (cnt > 0) {
            // slow fallback (tile overflows PKCAP): depth-2 scalar pipeline
            const unsigned* xrow = (const unsigned*)xb + lane;
            unsigned pA = packed[begg], pB = 0, rA = xrow[(size_t)(pA & 0xFFFFu) * 64];
            if (cnt > 1) pB = packed[begg + 1];
            for (int i = 0; i < cnt; ++i) {
                unsigned pC = (i + 2 < cnt) ? packed[begg + i + 2] : 0u;
                unsigned rB = xrow[(size_t)(pB & 0xFFFFu) * 64];
                float xlo = __uint_as_float(rA << 16);
                float xhi = __uint_as_float(rA & 0xFFFF0000u);
                int et = pA >> 16;
                const float4* cp = (const float4*)(comp + et * NBASIS);
                float4 cwa = cp[0];
                float4 cwb = cp[1];
                a0[0] += cwa.x * xlo; a1[0] += cwa.x * xhi;
                a0[1] += cwa.y * xlo; a1[1] += cwa.y * xhi;
                a0[2] += cwa.z * xlo; a1[2] += cwa.z * xhi;
                a0[3] += cwa.w * xlo; a1[3] += cwa.w * xhi;
                a0[4] += cwb.x * xlo; a1[4] += cwb.x * xhi;
                a0[5] += cwb.y * xlo; a1[5] += cwb.y * xhi;
                a0[6] += cwb.z * xlo; a1[6] += cwb.z * xhi;
                a0[7] += cwb.w * xlo; a1[7] += cwb.w * xhi;
                pA = pB; pB = pC; rA = rB;
            }
        }

        float inv = 1.f / (float)(cnt < 1 ? 1 : cnt);
#pragma unroll
        for (int b = 0; b < NBASIS; ++b) {
            unsigned lo = (unsigned)(ushort)f2bf(a0[b] * inv);
            unsigned hi = (unsigned)(ushort)f2bf(a1[b] * inv);
            unsigned byteoff = (unsigned)(row * 2048 + b * 256 + lane * 4);
            byteoff ^= (unsigned)((row & 7) << 4);   // bank swizzle
            *(unsigned*)((char*)Gl + byteoff) = lo | (hi << 16);
        }
    }
    __syncthreads();

    // ---- phase 2: MFMA GEMM (wave = one 16-col group x all 16 rows) ----
    int l15 = lane & 15, lhi = lane >> 4;
    int c = wid;                              // col-group 0..7

    fx4 acc0 = (fx4){0.f, 0.f, 0.f, 0.f};    // rows 0..15

    const sh8* W8 = (const sh8*)Wfb;

#pragma unroll
    for (int ks = 0; ks < 9; ++ks) {
        sh8 a0f[4];
        if (ks < 8) {
#pragma unroll
            for (int kk = 0; kk < 4; ++kk) {
                int ar0 = l15;
                unsigned bo0 = (unsigned)(ar0 * 2048 + ks * 256 + kk * 64 + lhi * 16);
                bo0 ^= (unsigned)((ar0 & 7) << 4);
                a0f[kk] = *(const sh8*)((const char*)Gl + bo0);
            }
        } else {
#pragma unroll
            for (int kk = 0; kk < 4; ++kk) {
                a0f[kk] = *(const sh8*)(xb + (size_t)(tile0 + l15) * 128 + lhi * 8 + kk * 32);
            }
        }
#pragma unroll
        for (int kk = 0; kk < 4; ++kk) {
            sh8 b = W8[(size_t)ks * 2048 + (size_t)((c * 4 + kk) * 64 + lane)];
            acc0 = __builtin_amdgcn_mfma_f32_16x16x32_bf16(a0f[kk], b, acc0, 0, 0, 0);
        }
    }

    // bias + act + store
    int col = c * 16 + l15;
    float bv = bias[col];
    int orow0 = tile0 + lhi * 4;
#pragma unroll
    for (int j = 0; j < 4; ++j) {
        float v = acc0[j] + bv;
        if (act) {
            v = tanhf(v);
            outbf[(size_t)(orow0 + j) * 128 + col] = (ushort)f2bf(v);
        } else {
            outf[(size_t)(orow0 + j) * 128 + col] = v;
        }
    }
}

__global__ void k_rel(const float* __restrict__ rel, const float* __restrict__ wrel,
                      float* __restrict__ out, int nrows) {
    int idx = blockIdx.x * 256 + threadIdx.x;
    if (idx >= nrows * DIM) return;
    int j = idx >> 7, o = idx & 127;
    float s = 0.f;
    for (int i = 0; i < DIM; ++i) s += rel[j * DIM + i] * wrel[i * DIM + o];
    out[idx] = s;
}

extern "C" void kernel_launch(void* const* d_in, const int* in_sizes, int n_in,
                              void* d_out, int out_size, void* d_ws, size_t ws_size,
                              hipStream_t stream) {
    const int* edge_index = (const int*)d_in[0];
    const int* edge_type  = (const int*)d_in[1];
    const float* init_embed = (const float*)d_in[2];
    const float* init_rel   = (const float*)d_in[3];
    const float* w_rel      = (const float*)d_in[4];
    const float* comp1  = (const float*)d_in[5];
    const float* basis1 = (const float*)d_in[6];
    const float* root1  = (const float*)d_in[7];
    const float* bias1  = (const float*)d_in[8];
    const float* comp2  = (const float*)d_in[9];
    const float* basis2 = (const float*)d_in[10];
    const float* root2  = (const float*)d_in[11];
    const float* bias2  = (const float*)d_in[12];

    int E = in_sizes[1];
    const int* src = edge_index;
    const int* dst = edge_index + E;
    int relrows = in_sizes[3] / DIM;   // 40

    // workspace layout (16B-aligned regions)
    short* Wfb1 = (short*)d_ws;                          // 9*16384 shorts
    short* Wfb2 = Wfb1 + (size_t)9 * 16384;
    ushort* xb  = (ushort*)(Wfb2 + (size_t)9 * 16384);   // 40000*128 bf16
    ushort* hb  = xb + (size_t)NENT * DIM;               // 40000*128 bf16
    int* hist   = (int*)(hb + (size_t)NENT * DIM);       // 40000 (pad 40004)
    int* offs   = hist + 40004;
    int* cursor = offs + 40004;
    int* bsum   = cursor + 40004;                        // 157 (pad 160)
    unsigned* packed = (unsigned*)(bsum + 160);          // E

    float* outx = (float*)d_out;
    float* outr = outx + (size_t)NENT * DIM;

    hipMemsetAsync(hist, 0, NENT * sizeof(int), stream);

    k_tobf<<<(NENT * DIM / 4 + 255) / 256, 256, 0, stream>>>(init_embed, xb, NENT * DIM);
    k_wfrag9<<<(9 * 16384 + 255) / 256, 256, 0, stream>>>(basis1, root1, Wfb1);
    k_wfrag9<<<(9 * 16384 + 255) / 256, 256, 0, stream>>>(basis2, root2, Wfb2);
    k_hist<<<(E + 255) / 256, 256, 0, stream>>>(dst, E, hist);
    k_scan1<<<SCANBLK, 256, 0, stream>>>(hist, offs, bsum);
    k_scan2<<<1, 256, 0, stream>>>(bsum);
    k_scan3<<<SCANBLK, 256, 0, stream>>>(offs, cursor, bsum, E);
    k_scatter<<<(E + 255) / 256, 256, 0, stream>>>(edge_type, src, dst, E, cursor, packed);

    // layer 1: hb = bf16(tanh(gather@W~1 + x@root1 + bias1))
    k_fused<<<NENT / TILE, 512, 0, stream>>>(xb, packed, offs, comp1, Wfb1, bias1,
                                             hb, outx, 1);
    // layer 2: out = gather@W~2 + h@root2 + bias2 (f32 to d_out)
    k_fused<<<NENT / TILE, 512, 0, stream>>>(hb, packed, offs, comp2, Wfb2, bias2,
                                             hb, outx, 0);

    // relation output: r = init_rel @ w_rel
    k_rel<<<(relrows * DIM + 255) / 256, 256, 0, stream>>>(init_rel, w_rel, outr, relrows);
}

// Round 18
// 219.467 us; speedup vs baseline: 1.4941x; 1.0395x over previous
//
#include <hip/hip_runtime.h>
#include <hip/hip_bf16.h>

#define NENT 40000
#define NREL 20
#define DIM 128
#define NBASIS 8
#define TILE 16                // nodes per fused block (32KB G tile -> 4 blocks/CU)
#define PKCAP 512              // LDS-staged packed entries per tile (avg ~256)
#define SCANBLK 157            // ceil(40000/256)

typedef __attribute__((ext_vector_type(8))) short sh8;
typedef __attribute__((ext_vector_type(4))) float fx4;
typedef __attribute__((ext_vector_type(2))) float f32x2;

__device__ __forceinline__ short f2bf(float f) {
    union { __hip_bfloat16 h; short s; } u;
    u.h = __float2bfloat16(f);
    return u.s;
}

// ---- fused prelude: tobf | wfrag9(x2) | hist | rel, branched by block range ----
__device__ __forceinline__ void d_tobf(int b, int t, const float* __restrict__ x,
                                       ushort* __restrict__ xb) {
    int i = (b * 256 + t) * 4;
    float4 v = *(const float4*)(x + i);
    ushort4 o;
    o.x = (ushort)f2bf(v.x); o.y = (ushort)f2bf(v.y);
    o.z = (ushort)f2bf(v.z); o.w = (ushort)f2bf(v.w);
    *(ushort4*)(xb + i) = o;
}

__device__ __forceinline__ void d_wfrag9(int b, int tt, const float* __restrict__ basis,
                                         const float* __restrict__ root,
                                         short* __restrict__ Wfb) {
    int t = b * 256 + tt;
    int ks = t / 16384;
    int rem = t & 16383;
    int i = rem >> 7, o = rem & 127;
    float v = (ks < 8) ? basis[ks * 16384 + i * 128 + o] : root[i * 128 + o];
    int c = o >> 4, l15 = o & 15;
    int kk = i >> 5, lhi = (i >> 3) & 3, e = i & 7;
    int lane = l15 + lhi * 16;
    Wfb[(size_t)ks * 16384 + (size_t)(((c * 4 + kk) * 64 + lane) << 3) + e] = f2bf(v);
}

__global__ void k_prep(const float* __restrict__ x, ushort* __restrict__ xb,
                       const float* __restrict__ basis1, const float* __restrict__ root1,
                       short* __restrict__ Wfb1,
                       const float* __restrict__ basis2, const float* __restrict__ root2,
                       short* __restrict__ Wfb2,
                       const int* __restrict__ dst, int E, int* __restrict__ hist,
                       const float* __restrict__ rel, const float* __restrict__ wrel,
                       float* __restrict__ outr, int relrows) {
    int b = blockIdx.x, t = threadIdx.x;
    if (b < 5000) {                       // tobf: 40000*128/4/256
        d_tobf(b, t, x, xb);
    } else if (b < 5576) {                // wfrag9 layer 1
        d_wfrag9(b - 5000, t, basis1, root1, Wfb1);
    } else if (b < 6152) {                // wfrag9 layer 2
        d_wfrag9(b - 5576, t, basis2, root2, Wfb2);
    } else if (b < 8652) {                // hist: 640000/256
        int e = (b - 6152) * 256 + t;
        if (e < E) atomicAdd(&hist[dst[e]], 1);
    } else {                              // rel GEMM: relrows*128
        int idx = (b - 8652) * 256 + t;
        if (idx < relrows * DIM) {
            int j = idx >> 7, o = idx & 127;
            float s = 0.f;
            for (int i = 0; i < DIM; ++i) s += rel[j * DIM + i] * wrel[i * DIM + o];
            outr[idx] = s;
        }
    }
}

// -------- 3-phase parallel scan over NENT bins --------
__global__ void k_scan1(const int* __restrict__ hist, int* __restrict__ offs,
                        int* __restrict__ bsum) {
    __shared__ int ps[256];
    int t = threadIdx.x;
    int i = blockIdx.x * 256 + t;
    int v = (i < NENT) ? hist[i] : 0;
    ps[t] = v;
    __syncthreads();
    for (int off = 1; off < 256; off <<= 1) {
        int u = (t >= off) ? ps[t - off] : 0;
        __syncthreads();
        ps[t] += u;
        __syncthreads();
    }
    if (i < NENT) offs[i] = ps[t] - v;
    if (t == 255) bsum[blockIdx.x] = ps[255];
}

__global__ void k_scan2(int* __restrict__ bsum) {
    __shared__ int ps[256];
    int t = threadIdx.x;
    int v = (t < SCANBLK) ? bsum[t] : 0;
    ps[t] = v;
    __syncthreads();
    for (int off = 1; off < 256; off <<= 1) {
        int u = (t >= off) ? ps[t - off] : 0;
        __syncthreads();
        ps[t] += u;
        __syncthreads();
    }
    if (t < SCANBLK) bsum[t] = ps[t] - v;
}

__global__ void k_scan3(int* __restrict__ offs, int* __restrict__ cursor,
                        const int* __restrict__ bsum, int E) {
    int i = blockIdx.x * 256 + threadIdx.x;
    if (i < NENT) {
        int o = offs[i] + bsum[blockIdx.x];
        offs[i] = o;
        cursor[i] = o;
    }
    if (i == 0) offs[NENT] = E;
}

// counting-sort by dst: packed = src | et<<16
__global__ void k_scatter(const int* __restrict__ et, const int* __restrict__ srcA,
                          const int* __restrict__ dstA, int E,
                          int* __restrict__ cursor, unsigned* __restrict__ packed) {
    int e = blockIdx.x * 256 + threadIdx.x;
    if (e >= E) return;
    int pos = atomicAdd(&cursor[dstA[e]], 1);
    packed[pos] = (unsigned)srcA[e] | ((unsigned)et[e] << 16);
}

// pinned async load, saddr form: scalar 64-bit base + per-lane 32-bit offset
#define GLDS(dst, voff, sbase)                                             \
    asm volatile("global_load_dword %0, %1, %2"                            \
                 : "=v"(dst) : "v"(voff), "s"(sbase))

#define WAITV(N)                                                           \
    do {                                                                   \
        asm volatile("s_waitcnt vmcnt(" #N ")" ::: "memory");              \
        __builtin_amdgcn_sched_barrier(0);                                 \
    } while (0)

// packed 2-wide FMA core: av[b] = {lo-col acc, hi-col acc}; 8 v_pk_fma_f32
#define FMA8(AV, CWA, CWB, XP)                                             \
    AV[0] += (f32x2){(CWA).x, (CWA).x} * (XP);                             \
    AV[1] += (f32x2){(CWA).y, (CWA).y} * (XP);                             \
    AV[2] += (f32x2){(CWA).z, (CWA).z} * (XP);                             \
    AV[3] += (f32x2){(CWA).w, (CWA).w} * (XP);                             \
    AV[4] += (f32x2){(CWB).x, (CWB).x} * (XP);                             \
    AV[5] += (f32x2){(CWB).y, (CWB).y} * (XP);                             \
    AV[6] += (f32x2){(CWB).z, (CWB).z} * (XP);                             \
    AV[7] += (f32x2){(CWB).w, (CWB).w} * (XP);

// Fused RGCN layer: block = 16 dst nodes, 8 waves, wave = 2 nodes.
// Phase 1 (R17 structure): scalar-pipe metadata, saddr-pinned 8-deep
//   ping-pong row loads, counted vmcnt; FMA core now f32x2 (v_pk_fma_f32).
// Phase 2: C[16x128] = [G_lds(1024) | x(128)] @ Wfb + bias via MFMA.
__global__ __launch_bounds__(512) void k_fused(
    const ushort* __restrict__ xb, const unsigned* __restrict__ packed,
    const int* __restrict__ offs, const float* __restrict__ comp,
    const short* __restrict__ Wfb, const float* __restrict__ bias,
    ushort* __restrict__ outbf, float* __restrict__ outf, int act) {
    __shared__ __align__(16) ushort Gl[TILE * 1024];   // 32KB
    __shared__ __align__(16) unsigned pkl[PKCAP];      // 2KB

    int t = threadIdx.x;
    int lane = t & 63, wid = t >> 6;
    unsigned lane4 = (unsigned)(lane * 4);

    int tile0 = blockIdx.x * TILE;
    int base = offs[tile0];
    int totE = offs[tile0 + TILE] - base;
    for (int i = t; i < totE && i < PKCAP; i += 512) pkl[i] = packed[base + i];
    __syncthreads();

    // ---- phase 1: gather (2 nodes per wave, scalar-metadata pipeline) ----
    bool fast = (totE <= PKCAP);
    for (int sub = 0; sub < 2; ++sub) {
        int row = wid * 2 + sub;             // 0..15
        int n = tile0 + row;
        int begg = offs[n];
        int cnt = offs[n + 1] - begg;
        int begl = begg - base;

        f32x2 av[NBASIS];
#pragma unroll
        for (int b = 0; b < NBASIS; ++b) av[b] = (f32x2){0.f, 0.f};

        if (cnt > 0 && fast) {
            int sbA[8], seA[8], sbB[8], seB[8];
            unsigned rA[8], rB[8];

            auto ldp = [&](int i0, int (&sb)[8], int (&se)[8]) {
#pragma unroll
                for (int u = 0; u < 8; ++u) {
                    int i = i0 + u;
                    int li = begl + (i < cnt ? i : 0);   // clamp: L1-hot row
                    unsigned p = __builtin_amdgcn_readfirstlane(pkl[li]);
                    sb[u] = (int)(p & 0xFFFFu) * 256;    // scalar byte offset
                    se[u] = (int)(p >> 16);
                }
            };
            auto issue = [&](const int (&sb)[8], unsigned (&r)[8]) {
#pragma unroll
                for (int u = 0; u < 8; ++u) {
                    const char* bp = (const char*)xb + sb[u];   // uniform base
                    GLDS(r[u], lane4, bp);
                }
            };
            auto proc = [&](int i0, const int (&se)[8], const unsigned (&r)[8]) {
#pragma unroll
                for (int u = 0; u < 8; ++u) {
                    if (i0 + u < cnt) {      // wave-uniform
                        const float4* cp = (const float4*)(comp + se[u] * NBASIS);
                        float4 cwa = cp[0];  // scalar-cache loads
                        float4 cwb = cp[1];
                        f32x2 xp = {__uint_as_float(r[u] << 16),
                                    __uint_as_float(r[u] & 0xFFFF0000u)};
                        FMA8(av, cwa, cwb, xp)
                    }
                }
            };

            ldp(0, sbA, seA); issue(sbA, rA);            // 8 outstanding
            int i0 = 0;
            while (i0 < cnt) {
                ldp(i0 + 8, sbB, seB); issue(sbB, rB);   // 16 outstanding
                WAITV(8);                                // batch A landed
                proc(i0, seA, rA);
                i0 += 8;
                if (i0 >= cnt) break;
                ldp(i0 + 8, sbA, seA); issue(sbA, rA);
                WAITV(8);                                // batch B landed
                proc(i0, seB, rB);
                i0 += 8;
            }
            asm volatile("s_waitcnt vmcnt(0)" ::: "memory");  // drain speculative
            __builtin_amdgcn_sched_barrier(0);
        } else if (cnt > 0) {
            // slow fallback (tile overflows PKCAP): depth-2 scalar pipeline
            const unsigned* xrow = (const unsigned*)xb + lane;
            unsigned pA = packed[begg], pB = 0, rA = xrow[(size_t)(pA & 0xFFFFu) * 64];
            if (cnt > 1) pB = packed[begg + 1];
            for (int i = 0; i < cnt; ++i) {
                unsigned pC = (i + 2 < cnt) ? packed[begg + i + 2] : 0u;
                unsigned rB = xrow[(size_t)(pB & 0xFFFFu) * 64];
                int et = pA >> 16;
                const float4* cp = (const float4*)(comp + et * NBASIS);
                float4 cwa = cp[0];
                float4 cwb = cp[1];
                f32x2 xp = {__uint_as_float(rA << 16),
                            __uint_as_float(rA & 0xFFFF0000u)};
                FMA8(av, cwa, cwb, xp)
                pA = pB; pB = pC; rA = rB;
            }
        }

        float inv = 1.f / (float)(cnt < 1 ? 1 : cnt);
#pragma unroll
        for (int b = 0; b < NBASIS; ++b) {
            unsigned lo = (unsigned)(ushort)f2bf(av[b][0] * inv);
            unsigned hi = (unsigned)(ushort)f2bf(av[b][1] * inv);
            unsigned byteoff = (unsigned)(row * 2048 + b * 256 + lane * 4);
            byteoff ^= (unsigned)((row & 7) << 4);   // bank swizzle
            *(unsigned*)((char*)Gl + byteoff) = lo | (hi << 16);
        }
    }
    __syncthreads();

    // ---- phase 2: MFMA GEMM (wave = one 16-col group x all 16 rows) ----
    int l15 = lane & 15, lhi = lane >> 4;
    int c = wid;                              // col-group 0..7

    fx4 acc0 = (fx4){0.f, 0.f, 0.f, 0.f};    // rows 0..15

    const sh8* W8 = (const sh8*)Wfb;

#pragma unroll
    for (int ks = 0; ks < 9; ++ks) {
        sh8 a0f[4];
        if (ks < 8) {
#pragma unroll
            for (int kk = 0; kk < 4; ++kk) {
                int ar0 = l15;
                unsigned bo0 = (unsigned)(ar0 * 2048 + ks * 256 + kk * 64 + lhi * 16);
                bo0 ^= (unsigned)((ar0 & 7) << 4);
                a0f[kk] = *(const sh8*)((const char*)Gl + bo0);
            }
        } else {
#pragma unroll
            for (int kk = 0; kk < 4; ++kk) {
                a0f[kk] = *(const sh8*)(xb + (size_t)(tile0 + l15) * 128 + lhi * 8 + kk * 32);
            }
        }
#pragma unroll
        for (int kk = 0; kk < 4; ++kk) {
            sh8 b = W8[(size_t)ks * 2048 + (size_t)((c * 4 + kk) * 64 + lane)];
            acc0 = __builtin_amdgcn_mfma_f32_16x16x32_bf16(a0f[kk], b, acc0, 0, 0, 0);
        }
    }

    // bias + act + store
    int col = c * 16 + l15;
    float bv = bias[col];
    int orow0 = tile0 + lhi * 4;
#pragma unroll
    for (int j = 0; j < 4; ++j) {
        float v = acc0[j] + bv;
        if (act) {
            v = tanhf(v);
            outbf[(size_t)(orow0 + j) * 128 + col] = (ushort)f2bf(v);
        } else {
            outf[(size_t)(orow0 + j) * 128 + col] = v;
        }
    }
}

extern "C" void kernel_launch(void* const* d_in, const int* in_sizes, int n_in,
                              void* d_out, int out_size, void* d_ws, size_t ws_size,
                              hipStream_t stream) {
    const int* edge_index = (const int*)d_in[0];
    const int* edge_type  = (const int*)d_in[1];
    const float* init_embed = (const float*)d_in[2];
    const float* init_rel   = (const float*)d_in[3];
    const float* w_rel      = (const float*)d_in[4];
    const float* comp1  = (const float*)d_in[5];
    const float* basis1 = (const float*)d_in[6];
    const float* root1  = (const float*)d_in[7];
    const float* bias1  = (const float*)d_in[8];
    const float* comp2  = (const float*)d_in[9];
    const float* basis2 = (const float*)d_in[10];
    const float* root2  = (const float*)d_in[11];
    const float* bias2  = (const float*)d_in[12];

    int E = in_sizes[1];
    const int* src = edge_index;
    const int* dst = edge_index + E;
    int relrows = in_sizes[3] / DIM;   // 40

    // workspace layout (16B-aligned regions)
    short* Wfb1 = (short*)d_ws;                          // 9*16384 shorts
    short* Wfb2 = Wfb1 + (size_t)9 * 16384;
    ushort* xb  = (ushort*)(Wfb2 + (size_t)9 * 16384);   // 40000*128 bf16
    ushort* hb  = xb + (size_t)NENT * DIM;               // 40000*128 bf16
    int* hist   = (int*)(hb + (size_t)NENT * DIM);       // 40000 (pad 40004)
    int* offs   = hist + 40004;
    int* cursor = offs + 40004;
    int* bsum   = cursor + 40004;                        // 157 (pad 160)
    unsigned* packed = (unsigned*)(bsum + 160);          // E

    float* outx = (float*)d_out;
    float* outr = outx + (size_t)NENT * DIM;

    hipMemsetAsync(hist, 0, NENT * sizeof(int), stream);

    int relblocks = (relrows * DIM + 255) / 256;         // 20 for 40 rows
    k_prep<<<8652 + relblocks, 256, 0, stream>>>(
        init_embed, xb, basis1, root1, Wfb1, basis2, root2, Wfb2,
        dst, E, hist, init_rel, w_rel, outr, relrows);
    k_scan1<<<SCANBLK, 256, 0, stream>>>(hist, offs, bsum);
    k_scan2<<<1, 256, 0, stream>>>(bsum);
    k_scan3<<<SCANBLK, 256, 0, stream>>>(offs, cursor, bsum, E);
    k_scatter<<<(E + 255) / 256, 256, 0, stream>>>(edge_type, src, dst, E, cursor, packed);

    // layer 1: hb = bf16(tanh(gather@W~1 + x@root1 + bias1))
    k_fused<<<NENT / TILE, 512, 0, stream>>>(xb, packed, offs, comp1, Wfb1, bias1,
                                             hb, outx, 1);
    // layer 2: out = gather@W~2 + h@root2 + bias2 (f32 to d_out)
    k_fused<<<NENT / TILE, 512, 0, stream>>>(hb, packed, offs, comp2, Wfb2, bias2,
                                             hb, outx, 0);
}